// Round 14
// baseline (399.507 us; speedup 1.0000x reference)
//
#include <hip/hip_runtime.h>

#define F_IN 128
#define H    128
#define OUT  64
#define BN_EPS 1e-5f
#define BIN_BLOCKS 160
#define HIST_BLOCKS 256
#define BUF_CAP 64        // per-bucket LDS staging entries in k_bin
#define OUT_CAP 10240     // per-bucket LDS reorder buffer in k_placeB (40KB)

// ---------------- bf16 / fp16 helpers ----------------
__device__ inline float bflo(unsigned int v) { return __uint_as_float(v << 16); }
__device__ inline float bfhi(unsigned int v) { return __uint_as_float(v & 0xffff0000u); }
__device__ inline unsigned int pack_bf(float a, float b) {
    unsigned int ua = __float_as_uint(a), ub = __float_as_uint(b);
    ua = (ua + 0x7fffu + ((ua >> 16) & 1u)) >> 16;          // RNE
    ub = (ub + 0x7fffu + ((ub >> 16) & 1u)) >> 16;
    return ua | (ub << 16);
}
union f16u { unsigned short u; _Float16 f; };
__device__ inline unsigned pack_sw(int s, float w) {        // src:u16 | fp16 w:u16
    f16u c; c.f = (_Float16)w;
    return (unsigned)s | ((unsigned)c.u << 16);
}
__device__ inline float unpack_w(unsigned p) {
    f16u c; c.u = (unsigned short)(p >> 16);
    return (float)c.f;
}

// ---------------- bucket histogram: LDS agg -> per-block slice (no global atomics) ----------------
// Also zeroes the 512-float BN sums region (blocks 0,1).
__global__ __launch_bounds__(256) void k_hist(const int* __restrict__ dst, int* bhs,
                                              float* sums_all, int e) {
    __shared__ int h[128];
    const int t = threadIdx.x;
    if (t < 128) h[t] = 0;
    if (blockIdx.x < 2) sums_all[blockIdx.x * 256 + t] = 0.f;
    __syncthreads();
    for (int i = blockIdx.x * 256 + t; i < e; i += gridDim.x * 256)
        atomicAdd(&h[dst[i] >> 9], 1);
    __syncthreads();
    if (t < 128) bhs[blockIdx.x * 128 + t] = h[t];
}

// ---------------- prep: reduce slices -> bucket sizes -> bstart + staging starts ----------------
__global__ __launch_bounds__(256) void k_prep(const int* __restrict__ bhs,
                                              int* bstart, int* astart, int* gtail,
                                              int* rowptr, int nb, int n, int e) {
    __shared__ int part[256];
    __shared__ int bs[128];
    const int t = threadIdx.x;
    const int b = t & 127, half = t >> 7;
    int v = 0;
    for (int s = half * (HIST_BLOCKS / 2); s < (half + 1) * (HIST_BLOCKS / 2); s++)
        v += bhs[s * 128 + b];
    part[t] = v;
    __syncthreads();
    int tot = (t < 128) ? (part[t] + part[t + 128]) : 0;
    if (t < 128) bs[t] = tot;
    __syncthreads();
    for (int off = 1; off < 128; off <<= 1) {
        int x = (t < 128 && t >= off) ? bs[t - off] : 0;
        __syncthreads();
        if (t < 128) bs[t] += x;
        __syncthreads();
    }
    if (t < nb) {
        int excl = bs[t] - tot;                 // exclusive scan
        bstart[t] = excl;
        int a = ((excl + 15) & ~15) + 16 * t;   // 64B-aligned staging start, disjoint
        astart[t] = a;
        gtail[t] = a;
    }
    if (t == 0) { bstart[nb] = e; rowptr[n] = e; }
}

// ---------------- pass 1: LDS-binned scatter to staging (full 64B chunk flushes) ----------------
__global__ __launch_bounds__(256) void k_bin(const int* __restrict__ src, const int* __restrict__ dst,
                                             int* gtail, unsigned* ebuck, int e, int nb) {
    __shared__ unsigned buf[128 * BUF_CAP];  // 32 KB
    __shared__ int cnt[128];
    const int t = threadIdx.x;
    if (t < 128) cnt[t] = 0;
    __syncthreads();
    const int per = (e + gridDim.x - 1) / gridDim.x;
    const int lo = blockIdx.x * per;
    const int hi = min(e, lo + per);
    for (int base = lo; base < hi; base += 1024) {
#pragma unroll
        for (int k = 0; k < 4; k++) {
            int i = base + k * 256 + t;
            if (i < hi) {
                int d = dst[i];
                int b = d >> 9;
                unsigned entry = (unsigned)src[i] | ((unsigned)(d & 511) << 16);
                int slot = atomicAdd(&cnt[b], 1);
                if (slot < BUF_CAP) buf[b * BUF_CAP + slot] = entry;
                else {                               // overflow fallback (never for random input)
                    int pos = atomicAdd(&gtail[b], 1);
                    __builtin_nontemporal_store(entry, &ebuck[pos]);
                }
            }
        }
        __syncthreads();
        if (t < nb) {                                // flush full 16-entry chunks
            int c = cnt[t]; if (c > BUF_CAP) c = BUF_CAP;
            int full = c & ~15;
            if (full > 0) {
                int bp = atomicAdd(&gtail[t], full);
                for (int j = 0; j < full; j++)
                    __builtin_nontemporal_store(buf[t * BUF_CAP + j], &ebuck[bp + j]);
                int rem = c - full;
                for (int j = 0; j < rem; j++) buf[t * BUF_CAP + j] = buf[t * BUF_CAP + full + j];
                cnt[t] = rem;
            }
        }
        __syncthreads();
    }
    if (t < nb) {                                    // final drain (partial)
        int c = cnt[t]; if (c > BUF_CAP) c = BUF_CAP;
        if (c > 0) {
            int bp = atomicAdd(&gtail[t], c);
            for (int j = 0; j < c; j++)
                __builtin_nontemporal_store(buf[t * BUF_CAP + j], &ebuck[bp + j]);
        }
    }
}

// ---------------- pass 2a: per-bucket hist -> rowptr + dinv ----------------
__global__ __launch_bounds__(256) void k_placeA(const unsigned* __restrict__ ebuck,
                                                const int* __restrict__ astart,
                                                const int* __restrict__ gtail,
                                                const int* __restrict__ bstart,
                                                int* rowptr, float* dinv, int n) {
    __shared__ int hist[512];
    __shared__ int scn[512];
    const int b = blockIdx.x, t = threadIdx.x;
    hist[t] = 0; hist[t + 256] = 0;
    __syncthreads();
    const int s0 = astart[b], s1 = gtail[b];
    for (int i = s0 + t; i < s1; i += 256) atomicAdd(&hist[ebuck[i] >> 16], 1);
    __syncthreads();
    scn[t] = hist[t]; scn[t + 256] = hist[t + 256];
    __syncthreads();
    for (int off = 1; off < 512; off <<= 1) {
        int a = (t >= off) ? scn[t - off] : 0;
        int c = (t + 256 >= off) ? scn[t + 256 - off] : 0;
        __syncthreads();
        scn[t] += a; scn[t + 256] += c;
        __syncthreads();
    }
    const int nodebase = b << 9;
    const int base = bstart[b];
    int node = nodebase + t;
    if (node < n) { rowptr[node] = base + scn[t] - hist[t]; dinv[node] = rsqrtf((float)(hist[t] + 1)); }
    node = nodebase + 256 + t;
    if (node < n) { rowptr[node] = base + scn[t + 256] - hist[t + 256]; dinv[node] = rsqrtf((float)(hist[t + 256] + 1)); }
}

// ---------------- pass 2b: LDS reorder -> coalesced final epack with weights ----------------
__global__ __launch_bounds__(256) void k_placeB(const unsigned* __restrict__ ebuck,
                                                const int* __restrict__ astart,
                                                const int* __restrict__ gtail,
                                                const int* __restrict__ bstart,
                                                const float* __restrict__ dinv,
                                                unsigned* epack, int n) {
    __shared__ int hist[512];
    __shared__ int scn[512];
    __shared__ float dloc[512];
    __shared__ unsigned outb[OUT_CAP];       // 40 KB
    const int b = blockIdx.x, t = threadIdx.x;
    const int nodebase = b << 9;
    hist[t] = 0; hist[t + 256] = 0;
    dloc[t]       = (nodebase + t       < n) ? dinv[nodebase + t]       : 0.f;
    dloc[t + 256] = (nodebase + 256 + t < n) ? dinv[nodebase + 256 + t] : 0.f;
    __syncthreads();
    const int s0 = astart[b], s1 = gtail[b];
    for (int i = s0 + t; i < s1; i += 256) atomicAdd(&hist[ebuck[i] >> 16], 1);
    __syncthreads();
    scn[t] = hist[t]; scn[t + 256] = hist[t + 256];
    __syncthreads();
    for (int off = 1; off < 512; off <<= 1) {
        int a = (t >= off) ? scn[t - off] : 0;
        int c = (t + 256 >= off) ? scn[t + 256 - off] : 0;
        __syncthreads();
        scn[t] += a; scn[t + 256] += c;
        __syncthreads();
    }
    scn[t] -= hist[t]; scn[t + 256] -= hist[t + 256];   // exclusive
    hist[t] = 0; hist[t + 256] = 0;                     // reuse as bump counters
    __syncthreads();
    const int base = bstart[b];
    for (int i = s0 + t; i < s1; i += 256) {
        unsigned en = ebuck[i];
        int dlow = en >> 16;
        int s = en & 0xffffu;
        int pos = scn[dlow] + atomicAdd(&hist[dlow], 1);
        unsigned word = pack_sw(s, dinv[s] * dloc[dlow]);
        if (pos < OUT_CAP) outb[pos] = word;
        else __builtin_nontemporal_store(word, &epack[base + pos]);   // overflow fallback
    }
    __syncthreads();
    int total = s1 - s0; if (total > OUT_CAP) total = OUT_CAP;
    for (int j = t; j < total; j += 256) epack[base + j] = outb[j];
}

// ---------------- 32-row inner GEMM body: at[32][132] @ W[128x128] -> bf16 ----------------
__device__ inline void mm_core_32(const float (*at)[132], const float* __restrict__ W,
                                  unsigned int* __restrict__ outb, int r_base, int n, int tid) {
    const int c0 = (tid & 31) * 4;            // 32 groups x 4 = 128 cols
    const int r0 = (tid >> 5) * 4;            // 8 groups x 4 = 32 rows
    float acc[4][4];
#pragma unroll
    for (int r = 0; r < 4; r++)
#pragma unroll
        for (int c = 0; c < 4; c++) acc[r][c] = 0.0f;
#pragma unroll 4
    for (int k = 0; k < 128; k++) {
        float4 wv = *(const float4*)&W[k * 128 + c0];
#pragma unroll
        for (int r = 0; r < 4; r++) {
            float a = at[r0 + r][k];
            acc[r][0] += a * wv.x;
            acc[r][1] += a * wv.y;
            acc[r][2] += a * wv.z;
            acc[r][3] += a * wv.w;
        }
    }
#pragma unroll
    for (int r = 0; r < 4; r++) {
        int row = r_base + r0 + r;
        if (row < n) {
            uint2 pk = make_uint2(pack_bf(acc[r][0], acc[r][1]),
                                  pack_bf(acc[r][2], acc[r][3]));
            *(uint2*)&outb[(size_t)row * 64 + (c0 >> 1)] = pk;
        }
    }
}

// layer 1: fp32 A, no BN, 32-row tile
__global__ __launch_bounds__(256) void k_mm_f32(const float* __restrict__ A,
                                                const float* __restrict__ W,
                                                unsigned int* __restrict__ outb, int n) {
    __shared__ float at[32][132];
    const int tid = threadIdx.x;
    const int r_base = blockIdx.x * 32;
    const int rr = tid >> 3;                  // 32 rows, 8 threads/row
    const int row_g = r_base + rr;
#pragma unroll
    for (int j = 0; j < 4; j++) {
        int k0 = (tid & 7) * 4 + j * 32;
        float4 v = make_float4(0.f, 0.f, 0.f, 0.f);
        if (row_g < n) v = *(const float4*)&A[(size_t)row_g * 128 + k0];
        *(float4*)&at[rr][k0] = v;
    }
    __syncthreads();
    mm_core_32(at, W, outb, r_base, n, tid);
}

// ---------------- pull aggregation: 64 lanes/node, 16-deep then 8-deep unroll ----------------
__global__ __launch_bounds__(256) void k_gather_bf(const unsigned int* __restrict__ linb,
                                                   const float* __restrict__ dinv,
                                                   const int* __restrict__ rowptr,
                                                   const unsigned* __restrict__ epack,
                                                   unsigned int* __restrict__ outb, int n) {
    const int t = threadIdx.x & 63;                          // feats 2t, 2t+1
    int node = blockIdx.x * 4 + (threadIdx.x >> 6);
    if (node >= n) return;
    node = __builtin_amdgcn_readfirstlane(node);
    const float dd = dinv[node];
    int p0 = rowptr[node];
    int p1 = rowptr[node + 1];
    p0 = __builtin_amdgcn_readfirstlane(p0);
    p1 = __builtin_amdgcn_readfirstlane(p1);

    float a0 = 0.f, a1 = 0.f, b0 = 0.f, b1 = 0.f;
    float c0 = 0.f, c1 = 0.f, d0 = 0.f, d1 = 0.f;
    int p = p0;
    for (; p + 16 <= p1; p += 16) {
        unsigned ee[16];
#pragma unroll
        for (int j = 0; j < 16; j++) ee[j] = epack[p + j];
        unsigned vv[16];
#pragma unroll
        for (int j = 0; j < 16; j++) vv[j] = linb[(size_t)(ee[j] & 0xffffu) * 64 + t];
#pragma unroll
        for (int j = 0; j < 16; j += 4) {
            float w0 = unpack_w(ee[j]), w1 = unpack_w(ee[j+1]);
            float w2 = unpack_w(ee[j+2]), w3 = unpack_w(ee[j+3]);
            a0 += bflo(vv[j])   * w0; a1 += bfhi(vv[j])   * w0;
            b0 += bflo(vv[j+1]) * w1; b1 += bfhi(vv[j+1]) * w1;
            c0 += bflo(vv[j+2]) * w2; c1 += bfhi(vv[j+2]) * w2;
            d0 += bflo(vv[j+3]) * w3; d1 += bfhi(vv[j+3]) * w3;
        }
    }
    for (; p + 8 <= p1; p += 8) {
        unsigned e0 = epack[p+0], e1 = epack[p+1], e2 = epack[p+2], e3 = epack[p+3];
        unsigned e4 = epack[p+4], e5 = epack[p+5], e6 = epack[p+6], e7 = epack[p+7];
        unsigned v0 = linb[(size_t)(e0 & 0xffffu) * 64 + t];
        unsigned v1 = linb[(size_t)(e1 & 0xffffu) * 64 + t];
        unsigned v2 = linb[(size_t)(e2 & 0xffffu) * 64 + t];
        unsigned v3 = linb[(size_t)(e3 & 0xffffu) * 64 + t];
        unsigned v4 = linb[(size_t)(e4 & 0xffffu) * 64 + t];
        unsigned v5 = linb[(size_t)(e5 & 0xffffu) * 64 + t];
        unsigned v6 = linb[(size_t)(e6 & 0xffffu) * 64 + t];
        unsigned v7 = linb[(size_t)(e7 & 0xffffu) * 64 + t];
        float w0 = unpack_w(e0), w1 = unpack_w(e1), w2 = unpack_w(e2), w3 = unpack_w(e3);
        float w4 = unpack_w(e4), w5 = unpack_w(e5), w6 = unpack_w(e6), w7 = unpack_w(e7);
        a0 += bflo(v0) * w0; a1 += bfhi(v0) * w0;
        b0 += bflo(v1) * w1; b1 += bfhi(v1) * w1;
        c0 += bflo(v2) * w2; c1 += bfhi(v2) * w2;
        d0 += bflo(v3) * w3; d1 += bfhi(v3) * w3;
        a0 += bflo(v4) * w4; a1 += bfhi(v4) * w4;
        b0 += bflo(v5) * w5; b1 += bfhi(v5) * w5;
        c0 += bflo(v6) * w6; c1 += bfhi(v6) * w6;
        d0 += bflo(v7) * w7; d1 += bfhi(v7) * w7;
    }
    for (; p < p1; p++) {
        unsigned ep = epack[p];
        unsigned v = linb[(size_t)(ep & 0xffffu) * 64 + t];
        float w = unpack_w(ep);
        a0 += bflo(v) * w; a1 += bfhi(v) * w;
    }
    {   // self-loop
        unsigned vs = linb[(size_t)node * 64 + t];
        float wsl = dd * dd;
        a0 += bflo(vs) * wsl; a1 += bfhi(vs) * wsl;
    }
    float F0 = (a0 + b0) + (c0 + d0);
    float F1 = (a1 + b1) + (c1 + d1);
    outb[(size_t)node * 64 + t] = pack_bf(F0, F1);
}

// ---------------- column stats from bf16 rows ----------------
__global__ __launch_bounds__(256) void k_colstats_bf(const unsigned int* __restrict__ hb,
                                                     float* sums, int n) {
    __shared__ float red[4][4][64];          // {slo,shi,qlo,qhi}[sub][t]
    int t = threadIdx.x & 63, sub = threadIdx.x >> 6;
    int r1 = min(blockIdx.x * 256 + 256, n);
    float s0 = 0.f, s1 = 0.f, q0 = 0.f, q1 = 0.f;
    for (int r = blockIdx.x * 256 + sub; r < r1; r += 4) {
        unsigned int v = hb[(size_t)r * 64 + t];
        float a = bflo(v), b = bfhi(v);
        s0 += a; q0 += a * a;
        s1 += b; q1 += b * b;
    }
    red[0][sub][t] = s0; red[1][sub][t] = s1;
    red[2][sub][t] = q0; red[3][sub][t] = q1;
    __syncthreads();
    if (sub == 0) {
        float ts0 = red[0][0][t] + red[0][1][t] + red[0][2][t] + red[0][3][t];
        float ts1 = red[1][0][t] + red[1][1][t] + red[1][2][t] + red[1][3][t];
        float tq0 = red[2][0][t] + red[2][1][t] + red[2][2][t] + red[2][3][t];
        float tq1 = red[3][0][t] + red[3][1][t] + red[3][2][t] + red[3][3][t];
        atomicAdd(&sums[2 * t],           ts0);
        atomicAdd(&sums[2 * t + 1],       ts1);
        atomicAdd(&sums[128 + 2 * t],     tq0);
        atomicAdd(&sums[128 + 2 * t + 1], tq1);
    }
}

// derive BN scale/shift from sums into LDS (per-block; sums is cache-resident, 1 KB)
__device__ inline void bn_to_lds(const float* __restrict__ sums, const float* __restrict__ g,
                                 const float* __restrict__ be, float* sc_s, float* sh_s,
                                 float inv_n, int tid) {
    if (tid < 128) {
        float m  = sums[tid] * inv_n;
        float v  = sums[128 + tid] * inv_n - m * m;
        float rs = rsqrtf(v + BN_EPS);
        float s  = g[tid] * rs;
        sc_s[tid] = s;
        sh_s[tid] = be[tid] - m * s;
    }
}

// layers 2/3: bf16 raw conv input + per-block BN prep + fused BN+ReLU staging (32-row tile)
__global__ __launch_bounds__(256) void k_mm_bf_bn(const unsigned int* __restrict__ Ab,
                                                  const float* __restrict__ sums,
                                                  const float* __restrict__ g,
                                                  const float* __restrict__ be, float inv_n,
                                                  const float* __restrict__ W,
                                                  unsigned int* __restrict__ outb, int n) {
    __shared__ float at[32][132];
    __shared__ float sc_s[128], sh_s[128];
    const int tid = threadIdx.x;
    bn_to_lds(sums, g, be, sc_s, sh_s, inv_n, tid);
    __syncthreads();
    const int r_base = blockIdx.x * 32;
    const int rr = tid >> 3;                  // 32 rows, 8 threads/row
    const int row_g = r_base + rr;
#pragma unroll
    for (int j = 0; j < 2; j++) {
        int u0 = (tid & 7) * 4 + j * 32;      // uint index within row (64 uints)
        int k0 = u0 * 2;                      // feature index
        uint4 v = make_uint4(0u, 0u, 0u, 0u);
        if (row_g < n) v = *(const uint4*)&Ab[(size_t)row_g * 64 + u0];
        float4 s0 = *(const float4*)&sc_s[k0],   s1 = *(const float4*)&sc_s[k0 + 4];
        float4 h0 = *(const float4*)&sh_s[k0],   h1 = *(const float4*)&sh_s[k0 + 4];
        float4 lo, hi;
        lo.x = fmaxf(fmaf(bflo(v.x), s0.x, h0.x), 0.f);
        lo.y = fmaxf(fmaf(bfhi(v.x), s0.y, h0.y), 0.f);
        lo.z = fmaxf(fmaf(bflo(v.y), s0.z, h0.z), 0.f);
        lo.w = fmaxf(fmaf(bfhi(v.y), s0.w, h0.w), 0.f);
        hi.x = fmaxf(fmaf(bflo(v.z), s1.x, h1.x), 0.f);
        hi.y = fmaxf(fmaf(bfhi(v.z), s1.y, h1.y), 0.f);
        hi.z = fmaxf(fmaf(bflo(v.w), s1.z, h1.z), 0.f);
        hi.w = fmaxf(fmaf(bfhi(v.w), s1.w, h1.w), 0.f);
        *(float4*)&at[rr][k0]     = lo;
        *(float4*)&at[rr][k0 + 4] = hi;
    }
    __syncthreads();
    mm_core_32(at, W, outb, r_base, n, tid);
}

// ---------------- JK max + projection (32-row tile) ----------------
__global__ __launch_bounds__(256) void k_jk_final(const unsigned int* __restrict__ Bb,
                                                  const unsigned int* __restrict__ Cb,
                                                  const unsigned int* __restrict__ Db,
                                                  const float* __restrict__ sumsL1,
                                                  const float* __restrict__ g1, const float* __restrict__ be1,
                                                  const float* __restrict__ sumsL2,
                                                  const float* __restrict__ g2, const float* __restrict__ be2,
                                                  float inv_n,
                                                  const float* __restrict__ b3, const float* __restrict__ Wp,
                                                  const float* __restrict__ bp, float* __restrict__ out, int n) {
    __shared__ float at[32][132];
    __shared__ float sc1[128], sh1[128], sc2[128], sh2[128];
    const int tid = threadIdx.x;
    bn_to_lds(sumsL1, g1, be1, sc1, sh1, inv_n, tid);
    bn_to_lds(sumsL2, g2, be2, sc2, sh2, inv_n, tid);
    __syncthreads();
    const int r_base = blockIdx.x * 32;
    const int rr = tid >> 3;                  // 32 rows, 8 threads/row
    const int row_g = r_base + rr;
#pragma unroll
    for (int j = 0; j < 2; j++) {
        int u0 = (tid & 7) * 4 + j * 32;
        int k0 = u0 * 2;
        uint4 vb = make_uint4(0u,0u,0u,0u), vc = vb, vd = vb;
        if (row_g < n) {
            vb = *(const uint4*)&Bb[(size_t)row_g * 64 + u0];
            vc = *(const uint4*)&Cb[(size_t)row_g * 64 + u0];
            vd = *(const uint4*)&Db[(size_t)row_g * 64 + u0];
        }
        float bv[8] = {bflo(vb.x), bfhi(vb.x), bflo(vb.y), bfhi(vb.y),
                       bflo(vb.z), bfhi(vb.z), bflo(vb.w), bfhi(vb.w)};
        float cv[8] = {bflo(vc.x), bfhi(vc.x), bflo(vc.y), bfhi(vc.y),
                       bflo(vc.z), bfhi(vc.z), bflo(vc.w), bfhi(vc.w)};
        float dv[8] = {bflo(vd.x), bfhi(vd.x), bflo(vd.y), bfhi(vd.y),
                       bflo(vd.z), bfhi(vd.z), bflo(vd.w), bfhi(vd.w)};
#pragma unroll
        for (int i = 0; i < 8; i++) {
            int k = k0 + i;
            float h1 = fmaxf(fmaf(bv[i], sc1[k], sh1[k]), 0.f);
            float h2 = fmaxf(fmaf(cv[i], sc2[k], sh2[k]), 0.f);
            float h3 = dv[i] + b3[k];
            at[rr][k] = fmaxf(fmaxf(h1, h2), h3);
        }
    }
    __syncthreads();
    const int c0 = (tid & 15) * 4;            // 16 groups x 4 = 64 out cols
    const int r0 = (tid >> 4) * 2;            // 16 groups x 2 = 32 rows
    float acc[2][4];
#pragma unroll
    for (int r = 0; r < 2; r++)
#pragma unroll
        for (int c = 0; c < 4; c++) acc[r][c] = 0.0f;
#pragma unroll 4
    for (int k = 0; k < 128; k++) {
        float4 wv = *(const float4*)&Wp[k * 64 + c0];
#pragma unroll
        for (int r = 0; r < 2; r++) {
            float a = at[r0 + r][k];
            acc[r][0] += a * wv.x;
            acc[r][1] += a * wv.y;
            acc[r][2] += a * wv.z;
            acc[r][3] += a * wv.w;
        }
    }
    float4 bpv = *(const float4*)&bp[c0];
#pragma unroll
    for (int r = 0; r < 2; r++) {
        int row = r_base + r0 + r;
        if (row < n) {
            float4 o;
            o.x = acc[r][0] + bpv.x; o.y = acc[r][1] + bpv.y;
            o.z = acc[r][2] + bpv.z; o.w = acc[r][3] + bpv.w;
            *(float4*)&out[(size_t)row * 64 + c0] = o;
        }
    }
}

extern "C" void kernel_launch(void* const* d_in, const int* in_sizes, int n_in,
                              void* d_out, int out_size, void* d_ws, size_t ws_size,
                              hipStream_t stream) {
    const float* x   = (const float*)d_in[0];
    const int*   ei  = (const int*)d_in[1];
    const float* W1  = (const float*)d_in[2];
    // b1 (d_in[3]) cancels inside BatchNorm — skipped
    const float* g1  = (const float*)d_in[4];
    const float* be1 = (const float*)d_in[5];
    const float* W2  = (const float*)d_in[6];
    // b2 (d_in[7]) cancels — skipped
    const float* g2  = (const float*)d_in[8];
    const float* be2 = (const float*)d_in[9];
    const float* W3  = (const float*)d_in[10];
    const float* b3  = (const float*)d_in[11];
    const float* Wp  = (const float*)d_in[12];
    const float* bp  = (const float*)d_in[13];
    float* out = (float*)d_out;

    const int n = in_sizes[0] / F_IN;        // 50000 (< 65536: u16 src packing valid)
    const int e = in_sizes[1] / 2;           // 800000
    const int* src = ei;
    const int* dst = ei + e;
    const int nb = (n + 511) >> 9;           // 98 buckets of 512 nodes (nb <= 128)

    float* ws = (float*)d_ws;
    float*        dinv   = ws;                               // n
    unsigned int* Ab     = (unsigned int*)(ws + n);          // n*64  lin bf16
    unsigned int* Bb     = Ab + (size_t)n * 64;              // n*64  conv1 raw bf16
    unsigned int* Cb     = Bb + (size_t)n * 64;              // n*64  conv2 raw bf16
    unsigned int* Db     = Cb + (size_t)n * 64;              // n*64  conv3 raw bf16
    int*          rowptr = (int*)(Db + (size_t)n * 64);      // n+2
    int*          bstart = rowptr + n + 2;                   // nb+1
    int*          astart = bstart + nb + 1;                  // nb+1
    int*          gtail  = astart + nb + 1;                  // nb
    unsigned*     epack  = (unsigned*)(gtail + nb);          // e
    unsigned*     ebuck  = epack + e;                        // e + 16*(nb+1) staging
    int*          bhs    = (int*)(ebuck + e + 16 * (nb + 1)); // HIST_BLOCKS*128 slices
    float*        sumsL1 = (float*)(bhs + HIST_BLOCKS * 128); // 256 --+ zeroed in k_hist
    float*        sumsL2 = sumsL1 + 256;                      // 256 --+

    const int BT = 256;
    const int gN   = (n + BT - 1) / BT;                      // 196
    const int gMM  = (n + 31) / 32;                          // 1563 (32-row tiles)
    const int gG   = (n + 3) / 4;                            // 4 nodes (waves) / block
    const float inv_n = 1.0f / (float)n;

    // ----- layer-1 matmul (independent of CSR chain) -----
    k_mm_f32<<<gMM, 256, 0, stream>>>(x, W1, Ab, n);

    // ----- CSR build: slice hist (also zeroes sums) -> prep -> bin -> place -----
    k_hist<<<HIST_BLOCKS, 256, 0, stream>>>(dst, bhs, sumsL1, e);
    k_prep<<<1, 256, 0, stream>>>(bhs, bstart, astart, gtail, rowptr, nb, n, e);
    k_bin<<<BIN_BLOCKS, 256, 0, stream>>>(src, dst, gtail, ebuck, e, nb);
    k_placeA<<<nb, 256, 0, stream>>>(ebuck, astart, gtail, bstart, rowptr, dinv, n);
    k_placeB<<<nb, 256, 0, stream>>>(ebuck, astart, gtail, bstart, dinv, epack, n);

    // ----- layer 1 aggregate + stats -----
    k_gather_bf<<<gG, 256, 0, stream>>>(Ab, dinv, rowptr, epack, Bb, n);
    k_colstats_bf<<<gN, 256, 0, stream>>>(Bb, sumsL1, n);

    // ----- layer 2: lin2 = relu(bn1(Bb))@W2 ; aggregate ; stats -----
    k_mm_bf_bn<<<gMM, 256, 0, stream>>>(Bb, sumsL1, g1, be1, inv_n, W2, Ab, n);
    k_gather_bf<<<gG, 256, 0, stream>>>(Ab, dinv, rowptr, epack, Cb, n);
    k_colstats_bf<<<gN, 256, 0, stream>>>(Cb, sumsL2, n);

    // ----- layer 3: lin3 = relu(bn2(Cb))@W3 ; aggregate -----
    k_mm_bf_bn<<<gMM, 256, 0, stream>>>(Cb, sumsL2, g2, be2, inv_n, W3, Ab, n);
    k_gather_bf<<<gG, 256, 0, stream>>>(Ab, dinv, rowptr, epack, Db, n);

    // ----- JK max + projection -----
    k_jk_final<<<gMM, 256, 0, stream>>>(Bb, Cb, Db, sumsL1, g1, be1, sumsL2, g2, be2,
                                        inv_n, b3, Wp, bp, out, n);
}

// Round 15
// 336.424 us; speedup vs baseline: 1.1875x; 1.1875x over previous
//
#include <hip/hip_runtime.h>

#define F_IN 128
#define H    128
#define OUT  64
#define BN_EPS 1e-5f
#define BIN_BLOCKS 160
#define HIST_BLOCKS 256
#define BUF_CAP 64        // per-bucket LDS staging entries in k_bin
#define OUT_CAP 10240     // per-bucket LDS reorder buffer in k_placeB (40KB)

typedef __attribute__((ext_vector_type(8))) short bf16x8;
typedef __attribute__((ext_vector_type(4))) float f32x4;
union FragU { unsigned u[4]; bf16x8 f; };

// ---------------- bf16 / fp16 helpers ----------------
__device__ inline float bflo(unsigned int v) { return __uint_as_float(v << 16); }
__device__ inline float bfhi(unsigned int v) { return __uint_as_float(v & 0xffff0000u); }
__device__ inline unsigned int pack_bf(float a, float b) {
    unsigned int ua = __float_as_uint(a), ub = __float_as_uint(b);
    ua = (ua + 0x7fffu + ((ua >> 16) & 1u)) >> 16;          // RNE
    ub = (ub + 0x7fffu + ((ub >> 16) & 1u)) >> 16;
    return ua | (ub << 16);
}
union f16u { unsigned short u; _Float16 f; };
__device__ inline unsigned pack_sw(int s, float w) {        // src:u16 | fp16 w:u16
    f16u c; c.f = (_Float16)w;
    return (unsigned)s | ((unsigned)c.u << 16);
}
__device__ inline float unpack_w(unsigned p) {
    f16u c; c.u = (unsigned short)(p >> 16);
    return (float)c.f;
}

// ---------------- bucket histogram: LDS agg -> per-block slice (no global atomics) ----------------
__global__ __launch_bounds__(256) void k_hist(const int* __restrict__ dst, int* bhs,
                                              float* sums_all, int e) {
    __shared__ int h[128];
    const int t = threadIdx.x;
    if (t < 128) h[t] = 0;
    if (blockIdx.x < 2) sums_all[blockIdx.x * 256 + t] = 0.f;
    __syncthreads();
    for (int i = blockIdx.x * 256 + t; i < e; i += gridDim.x * 256)
        atomicAdd(&h[dst[i] >> 9], 1);
    __syncthreads();
    if (t < 128) bhs[blockIdx.x * 128 + t] = h[t];
}

// ---------------- prep: reduce slices -> bucket sizes -> bstart + staging starts ----------------
__global__ __launch_bounds__(256) void k_prep(const int* __restrict__ bhs,
                                              int* bstart, int* astart, int* gtail,
                                              int* rowptr, int nb, int n, int e) {
    __shared__ int part[256];
    __shared__ int bs[128];
    const int t = threadIdx.x;
    const int b = t & 127, half = t >> 7;
    int v = 0;
    for (int s = half * (HIST_BLOCKS / 2); s < (half + 1) * (HIST_BLOCKS / 2); s++)
        v += bhs[s * 128 + b];
    part[t] = v;
    __syncthreads();
    int tot = (t < 128) ? (part[t] + part[t + 128]) : 0;
    if (t < 128) bs[t] = tot;
    __syncthreads();
    for (int off = 1; off < 128; off <<= 1) {
        int x = (t < 128 && t >= off) ? bs[t - off] : 0;
        __syncthreads();
        if (t < 128) bs[t] += x;
        __syncthreads();
    }
    if (t < nb) {
        int excl = bs[t] - tot;                 // exclusive scan
        bstart[t] = excl;
        int a = ((excl + 15) & ~15) + 16 * t;   // 64B-aligned staging start, disjoint
        astart[t] = a;
        gtail[t] = a;
    }
    if (t == 0) { bstart[nb] = e; rowptr[n] = e; }
}

// ---------------- pass 1: LDS-binned scatter to staging (full 64B chunk flushes) ----------------
__global__ __launch_bounds__(256) void k_bin(const int* __restrict__ src, const int* __restrict__ dst,
                                             int* gtail, unsigned* ebuck, int e, int nb) {
    __shared__ unsigned buf[128 * BUF_CAP];  // 32 KB
    __shared__ int cnt[128];
    const int t = threadIdx.x;
    if (t < 128) cnt[t] = 0;
    __syncthreads();
    const int per = (e + gridDim.x - 1) / gridDim.x;
    const int lo = blockIdx.x * per;
    const int hi = min(e, lo + per);
    for (int base = lo; base < hi; base += 1024) {
#pragma unroll
        for (int k = 0; k < 4; k++) {
            int i = base + k * 256 + t;
            if (i < hi) {
                int d = dst[i];
                int b = d >> 9;
                unsigned entry = (unsigned)src[i] | ((unsigned)(d & 511) << 16);
                int slot = atomicAdd(&cnt[b], 1);
                if (slot < BUF_CAP) buf[b * BUF_CAP + slot] = entry;
                else {                               // overflow fallback (never for random input)
                    int pos = atomicAdd(&gtail[b], 1);
                    __builtin_nontemporal_store(entry, &ebuck[pos]);
                }
            }
        }
        __syncthreads();
        if (t < nb) {                                // flush full 16-entry chunks
            int c = cnt[t]; if (c > BUF_CAP) c = BUF_CAP;
            int full = c & ~15;
            if (full > 0) {
                int bp = atomicAdd(&gtail[t], full);
                for (int j = 0; j < full; j++)
                    __builtin_nontemporal_store(buf[t * BUF_CAP + j], &ebuck[bp + j]);
                int rem = c - full;
                for (int j = 0; j < rem; j++) buf[t * BUF_CAP + j] = buf[t * BUF_CAP + full + j];
                cnt[t] = rem;
            }
        }
        __syncthreads();
    }
    if (t < nb) {                                    // final drain (partial)
        int c = cnt[t]; if (c > BUF_CAP) c = BUF_CAP;
        if (c > 0) {
            int bp = atomicAdd(&gtail[t], c);
            for (int j = 0; j < c; j++)
                __builtin_nontemporal_store(buf[t * BUF_CAP + j], &ebuck[bp + j]);
        }
    }
}

// ---------------- pass 2a: per-bucket hist -> rowptr + dinv ----------------
__global__ __launch_bounds__(256) void k_placeA(const unsigned* __restrict__ ebuck,
                                                const int* __restrict__ astart,
                                                const int* __restrict__ gtail,
                                                const int* __restrict__ bstart,
                                                int* rowptr, float* dinv, int n) {
    __shared__ int hist[512];
    __shared__ int scn[512];
    const int b = blockIdx.x, t = threadIdx.x;
    hist[t] = 0; hist[t + 256] = 0;
    __syncthreads();
    const int s0 = astart[b], s1 = gtail[b];
    for (int i = s0 + t; i < s1; i += 256) atomicAdd(&hist[ebuck[i] >> 16], 1);
    __syncthreads();
    scn[t] = hist[t]; scn[t + 256] = hist[t + 256];
    __syncthreads();
    for (int off = 1; off < 512; off <<= 1) {
        int a = (t >= off) ? scn[t - off] : 0;
        int c = (t + 256 >= off) ? scn[t + 256 - off] : 0;
        __syncthreads();
        scn[t] += a; scn[t + 256] += c;
        __syncthreads();
    }
    const int nodebase = b << 9;
    const int base = bstart[b];
    int node = nodebase + t;
    if (node < n) { rowptr[node] = base + scn[t] - hist[t]; dinv[node] = rsqrtf((float)(hist[t] + 1)); }
    node = nodebase + 256 + t;
    if (node < n) { rowptr[node] = base + scn[t + 256] - hist[t + 256]; dinv[node] = rsqrtf((float)(hist[t + 256] + 1)); }
}

// ---------------- pass 2b: LDS reorder -> coalesced final epack with weights ----------------
__global__ __launch_bounds__(256) void k_placeB(const unsigned* __restrict__ ebuck,
                                                const int* __restrict__ astart,
                                                const int* __restrict__ gtail,
                                                const int* __restrict__ bstart,
                                                const float* __restrict__ dinv,
                                                unsigned* epack, int n) {
    __shared__ int hist[512];
    __shared__ int scn[512];
    __shared__ float dloc[512];
    __shared__ unsigned outb[OUT_CAP];       // 40 KB
    const int b = blockIdx.x, t = threadIdx.x;
    const int nodebase = b << 9;
    hist[t] = 0; hist[t + 256] = 0;
    dloc[t]       = (nodebase + t       < n) ? dinv[nodebase + t]       : 0.f;
    dloc[t + 256] = (nodebase + 256 + t < n) ? dinv[nodebase + 256 + t] : 0.f;
    __syncthreads();
    const int s0 = astart[b], s1 = gtail[b];
    for (int i = s0 + t; i < s1; i += 256) atomicAdd(&hist[ebuck[i] >> 16], 1);
    __syncthreads();
    scn[t] = hist[t]; scn[t + 256] = hist[t + 256];
    __syncthreads();
    for (int off = 1; off < 512; off <<= 1) {
        int a = (t >= off) ? scn[t - off] : 0;
        int c = (t + 256 >= off) ? scn[t + 256 - off] : 0;
        __syncthreads();
        scn[t] += a; scn[t + 256] += c;
        __syncthreads();
    }
    scn[t] -= hist[t]; scn[t + 256] -= hist[t + 256];   // exclusive
    hist[t] = 0; hist[t + 256] = 0;                     // reuse as bump counters
    __syncthreads();
    const int base = bstart[b];
    for (int i = s0 + t; i < s1; i += 256) {
        unsigned en = ebuck[i];
        int dlow = en >> 16;
        int s = en & 0xffffu;
        int pos = scn[dlow] + atomicAdd(&hist[dlow], 1);
        unsigned word = pack_sw(s, dinv[s] * dloc[dlow]);
        if (pos < OUT_CAP) outb[pos] = word;
        else __builtin_nontemporal_store(word, &epack[base + pos]);   // overflow fallback
    }
    __syncthreads();
    int total = s1 - s0; if (total > OUT_CAP) total = OUT_CAP;
    for (int j = t; j < total; j += 256) epack[base + j] = outb[j];
}

// ---------------- W -> bf16 MFMA B-fragment conversion (one-time per call) ----------------
// wf layout per W: uint4 index (ks*8+ct)*64 + lane; element j of frag = W[ks*32+(lane>>4)*8+j][ct*16+(lane&15)]
__global__ __launch_bounds__(256) void k_wconv(const float* __restrict__ W1,
                                               const float* __restrict__ W2,
                                               const float* __restrict__ W3,
                                               unsigned* __restrict__ wf) {
    int t = blockIdx.x * 256 + threadIdx.x;      // 0..6143
    int w = t >> 11;
    int rem = t & 2047;
    int ks = rem >> 9;
    int ct = (rem >> 6) & 7;
    int lane = rem & 63;
    const float* W = (w == 0) ? W1 : (w == 1) ? W2 : W3;
    int col = ct * 16 + (lane & 15);
    int kb = ks * 32 + (lane >> 4) * 8;
    uint4 pk;
    pk.x = pack_bf(W[(kb + 0) * 128 + col], W[(kb + 1) * 128 + col]);
    pk.y = pack_bf(W[(kb + 2) * 128 + col], W[(kb + 3) * 128 + col]);
    pk.z = pack_bf(W[(kb + 4) * 128 + col], W[(kb + 5) * 128 + col]);
    pk.w = pack_bf(W[(kb + 6) * 128 + col], W[(kb + 7) * 128 + col]);
    ((uint4*)(wf + (size_t)w * 8192))[(ks * 8 + ct) * 64 + lane] = pk;
}

// derive BN scale/shift from sums into LDS
__device__ inline void bn_to_lds(const float* __restrict__ sums, const float* __restrict__ g,
                                 const float* __restrict__ be, float* sc_s, float* sh_s,
                                 float inv_n, int tid) {
    if (tid < 128) {
        float m  = sums[tid] * inv_n;
        float v  = sums[128 + tid] * inv_n - m * m;
        float rs = rsqrtf(v + BN_EPS);
        float s  = g[tid] * rs;
        sc_s[tid] = s;
        sh_s[tid] = be[tid] - m * s;
    }
}

// ---------------- MFMA GEMM: C[n x 128] = act(A) @ W -> packed bf16 ----------------
// MODE 0: A fp32, no BN. MODE 1: A bf16-packed, fused BN+ReLU.
// 4 waves/block, 64 rows/block; wave computes 16x128 via 8 col-tiles x 4 k-steps of mfma 16x16x32.
template<int MODE>
__global__ __launch_bounds__(256) void k_mm_mfma(const void* __restrict__ Aptr,
                                                 const unsigned* __restrict__ wfrag,
                                                 const float* __restrict__ sums,
                                                 const float* __restrict__ g,
                                                 const float* __restrict__ be, float inv_n,
                                                 unsigned* __restrict__ outb, int n) {
    __shared__ float sc_s[128], sh_s[128];
    __shared__ float dtile[4][16][130];
    const int tid = threadIdx.x;
    if (MODE == 1) {
        bn_to_lds(sums, g, be, sc_s, sh_s, inv_n, tid);
        __syncthreads();
    }
    const int wave = tid >> 6, lane = tid & 63;
    const int r0 = blockIdx.x * 64 + wave * 16;
    const int arow = r0 + (lane & 15);
    const int koff = (lane >> 4) * 8;

    FragU afr[4];
    if (MODE == 0) {
        const float* A = (const float*)Aptr;
#pragma unroll
        for (int ks = 0; ks < 4; ks++) {
            float4 v0 = make_float4(0.f, 0.f, 0.f, 0.f), v1 = v0;
            if (arow < n) {
                v0 = *(const float4*)&A[(size_t)arow * 128 + ks * 32 + koff];
                v1 = *(const float4*)&A[(size_t)arow * 128 + ks * 32 + koff + 4];
            }
            afr[ks].u[0] = pack_bf(v0.x, v0.y);
            afr[ks].u[1] = pack_bf(v0.z, v0.w);
            afr[ks].u[2] = pack_bf(v1.x, v1.y);
            afr[ks].u[3] = pack_bf(v1.z, v1.w);
        }
    } else {
        const unsigned* Ab = (const unsigned*)Aptr;
#pragma unroll
        for (int ks = 0; ks < 4; ks++) {
            uint4 v = make_uint4(0u, 0u, 0u, 0u);
            if (arow < n) v = *(const uint4*)&Ab[(size_t)arow * 64 + ks * 16 + (lane >> 4) * 4];
            unsigned vv[4] = {v.x, v.y, v.z, v.w};
            const int kk = ks * 32 + koff;
#pragma unroll
            for (int q = 0; q < 4; q++) {
                int k0 = kk + 2 * q;
                float lo = fmaxf(fmaf(bflo(vv[q]), sc_s[k0],     sh_s[k0]),     0.f);
                float hi = fmaxf(fmaf(bfhi(vv[q]), sc_s[k0 + 1], sh_s[k0 + 1]), 0.f);
                afr[ks].u[q] = pack_bf(lo, hi);
            }
        }
    }

    const uint4* wf4 = (const uint4*)wfrag;
    const int drow = (lane >> 4) * 4;
#pragma unroll
    for (int ct = 0; ct < 8; ct++) {
        f32x4 acc = {0.f, 0.f, 0.f, 0.f};
#pragma unroll
        for (int ks = 0; ks < 4; ks++) {
            FragU b;
            *(uint4*)b.u = wf4[(ks * 8 + ct) * 64 + lane];
            acc = __builtin_amdgcn_mfma_f32_16x16x32_bf16(afr[ks].f, b.f, acc, 0, 0, 0);
        }
        const int dcol = ct * 16 + (lane & 15);
#pragma unroll
        for (int r = 0; r < 4; r++) dtile[wave][drow + r][dcol] = acc[r];
    }
    // wave-private transpose readback (no cross-wave sync needed)
    const int lr = lane >> 2;
    const int uc = (lane & 3) * 16;
    if (r0 + lr < n) {
#pragma unroll
        for (int q2 = 0; q2 < 4; q2++) {
            const float* s = &dtile[wave][lr][2 * uc + 8 * q2];
            uint4 pk;
            pk.x = pack_bf(s[0], s[1]);
            pk.y = pack_bf(s[2], s[3]);
            pk.z = pack_bf(s[4], s[5]);
            pk.w = pack_bf(s[6], s[7]);
            *(uint4*)&outb[(size_t)(r0 + lr) * 64 + uc + 4 * q2] = pk;
        }
    }
}

// ---------------- pull aggregation: 64 lanes/node, 16-deep then 8-deep unroll ----------------
__global__ __launch_bounds__(256) void k_gather_bf(const unsigned int* __restrict__ linb,
                                                   const float* __restrict__ dinv,
                                                   const int* __restrict__ rowptr,
                                                   const unsigned* __restrict__ epack,
                                                   unsigned int* __restrict__ outb, int n) {
    const int t = threadIdx.x & 63;                          // feats 2t, 2t+1
    int node = blockIdx.x * 4 + (threadIdx.x >> 6);
    if (node >= n) return;
    node = __builtin_amdgcn_readfirstlane(node);
    const float dd = dinv[node];
    int p0 = rowptr[node];
    int p1 = rowptr[node + 1];
    p0 = __builtin_amdgcn_readfirstlane(p0);
    p1 = __builtin_amdgcn_readfirstlane(p1);

    float a0 = 0.f, a1 = 0.f, b0 = 0.f, b1 = 0.f;
    float c0 = 0.f, c1 = 0.f, d0 = 0.f, d1 = 0.f;
    int p = p0;
    for (; p + 16 <= p1; p += 16) {
        unsigned ee[16];
#pragma unroll
        for (int j = 0; j < 16; j++) ee[j] = epack[p + j];
        unsigned vv[16];
#pragma unroll
        for (int j = 0; j < 16; j++) vv[j] = linb[(size_t)(ee[j] & 0xffffu) * 64 + t];
#pragma unroll
        for (int j = 0; j < 16; j += 4) {
            float w0 = unpack_w(ee[j]), w1 = unpack_w(ee[j+1]);
            float w2 = unpack_w(ee[j+2]), w3 = unpack_w(ee[j+3]);
            a0 += bflo(vv[j])   * w0; a1 += bfhi(vv[j])   * w0;
            b0 += bflo(vv[j+1]) * w1; b1 += bfhi(vv[j+1]) * w1;
            c0 += bflo(vv[j+2]) * w2; c1 += bfhi(vv[j+2]) * w2;
            d0 += bflo(vv[j+3]) * w3; d1 += bfhi(vv[j+3]) * w3;
        }
    }
    for (; p + 8 <= p1; p += 8) {
        unsigned e0 = epack[p+0], e1 = epack[p+1], e2 = epack[p+2], e3 = epack[p+3];
        unsigned e4 = epack[p+4], e5 = epack[p+5], e6 = epack[p+6], e7 = epack[p+7];
        unsigned v0 = linb[(size_t)(e0 & 0xffffu) * 64 + t];
        unsigned v1 = linb[(size_t)(e1 & 0xffffu) * 64 + t];
        unsigned v2 = linb[(size_t)(e2 & 0xffffu) * 64 + t];
        unsigned v3 = linb[(size_t)(e3 & 0xffffu) * 64 + t];
        unsigned v4 = linb[(size_t)(e4 & 0xffffu) * 64 + t];
        unsigned v5 = linb[(size_t)(e5 & 0xffffu) * 64 + t];
        unsigned v6 = linb[(size_t)(e6 & 0xffffu) * 64 + t];
        unsigned v7 = linb[(size_t)(e7 & 0xffffu) * 64 + t];
        float w0 = unpack_w(e0), w1 = unpack_w(e1), w2 = unpack_w(e2), w3 = unpack_w(e3);
        float w4 = unpack_w(e4), w5 = unpack_w(e5), w6 = unpack_w(e6), w7 = unpack_w(e7);
        a0 += bflo(v0) * w0; a1 += bfhi(v0) * w0;
        b0 += bflo(v1) * w1; b1 += bfhi(v1) * w1;
        c0 += bflo(v2) * w2; c1 += bfhi(v2) * w2;
        d0 += bflo(v3) * w3; d1 += bfhi(v3) * w3;
        a0 += bflo(v4) * w4; a1 += bfhi(v4) * w4;
        b0 += bflo(v5) * w5; b1 += bfhi(v5) * w5;
        c0 += bflo(v6) * w6; c1 += bfhi(v6) * w6;
        d0 += bflo(v7) * w7; d1 += bfhi(v7) * w7;
    }
    for (; p < p1; p++) {
        unsigned ep = epack[p];
        unsigned v = linb[(size_t)(ep & 0xffffu) * 64 + t];
        float w = unpack_w(ep);
        a0 += bflo(v) * w; a1 += bfhi(v) * w;
    }
    {   // self-loop
        unsigned vs = linb[(size_t)node * 64 + t];
        float wsl = dd * dd;
        a0 += bflo(vs) * wsl; a1 += bfhi(vs) * wsl;
    }
    float F0 = (a0 + b0) + (c0 + d0);
    float F1 = (a1 + b1) + (c1 + d1);
    outb[(size_t)node * 64 + t] = pack_bf(F0, F1);
}

// ---------------- column stats from bf16 rows ----------------
__global__ __launch_bounds__(256) void k_colstats_bf(const unsigned int* __restrict__ hb,
                                                     float* sums, int n) {
    __shared__ float red[4][4][64];          // {slo,shi,qlo,qhi}[sub][t]
    int t = threadIdx.x & 63, sub = threadIdx.x >> 6;
    int r1 = min(blockIdx.x * 256 + 256, n);
    float s0 = 0.f, s1 = 0.f, q0 = 0.f, q1 = 0.f;
    for (int r = blockIdx.x * 256 + sub; r < r1; r += 4) {
        unsigned int v = hb[(size_t)r * 64 + t];
        float a = bflo(v), b = bfhi(v);
        s0 += a; q0 += a * a;
        s1 += b; q1 += b * b;
    }
    red[0][sub][t] = s0; red[1][sub][t] = s1;
    red[2][sub][t] = q0; red[3][sub][t] = q1;
    __syncthreads();
    if (sub == 0) {
        float ts0 = red[0][0][t] + red[0][1][t] + red[0][2][t] + red[0][3][t];
        float ts1 = red[1][0][t] + red[1][1][t] + red[1][2][t] + red[1][3][t];
        float tq0 = red[2][0][t] + red[2][1][t] + red[2][2][t] + red[2][3][t];
        float tq1 = red[3][0][t] + red[3][1][t] + red[3][2][t] + red[3][3][t];
        atomicAdd(&sums[2 * t],           ts0);
        atomicAdd(&sums[2 * t + 1],       ts1);
        atomicAdd(&sums[128 + 2 * t],     tq0);
        atomicAdd(&sums[128 + 2 * t + 1], tq1);
    }
}

// ---------------- JK max (per-block BN prep) + projection (64-row, round-12 version) ----------------
__global__ __launch_bounds__(256) void k_jk_final(const unsigned int* __restrict__ Bb,
                                                  const unsigned int* __restrict__ Cb,
                                                  const unsigned int* __restrict__ Db,
                                                  const float* __restrict__ sumsL1,
                                                  const float* __restrict__ g1, const float* __restrict__ be1,
                                                  const float* __restrict__ sumsL2,
                                                  const float* __restrict__ g2, const float* __restrict__ be2,
                                                  float inv_n,
                                                  const float* __restrict__ b3, const float* __restrict__ Wp,
                                                  const float* __restrict__ bp, float* __restrict__ out, int n) {
    __shared__ float at[64][132];
    __shared__ float sc1[128], sh1[128], sc2[128], sh2[128];
    const int tid = threadIdx.x;
    bn_to_lds(sumsL1, g1, be1, sc1, sh1, inv_n, tid);
    bn_to_lds(sumsL2, g2, be2, sc2, sh2, inv_n, tid);
    __syncthreads();
    const int r_base = blockIdx.x * 64;
    const int rr = tid >> 2;
    const int row_g = r_base + rr;
#pragma unroll
    for (int j = 0; j < 4; j++) {
        int u0 = (tid & 3) * 4 + j * 16;
        int k0 = u0 * 2;
        uint4 vb = make_uint4(0u,0u,0u,0u), vc = vb, vd = vb;
        if (row_g < n) {
            vb = *(const uint4*)&Bb[(size_t)row_g * 64 + u0];
            vc = *(const uint4*)&Cb[(size_t)row_g * 64 + u0];
            vd = *(const uint4*)&Db[(size_t)row_g * 64 + u0];
        }
        float bv[8] = {bflo(vb.x), bfhi(vb.x), bflo(vb.y), bfhi(vb.y),
                       bflo(vb.z), bfhi(vb.z), bflo(vb.w), bfhi(vb.w)};
        float cv[8] = {bflo(vc.x), bfhi(vc.x), bflo(vc.y), bfhi(vc.y),
                       bflo(vc.z), bfhi(vc.z), bflo(vc.w), bfhi(vc.w)};
        float dv[8] = {bflo(vd.x), bfhi(vd.x), bflo(vd.y), bfhi(vd.y),
                       bflo(vd.z), bfhi(vd.z), bflo(vd.w), bfhi(vd.w)};
#pragma unroll
        for (int i = 0; i < 8; i++) {
            int k = k0 + i;
            float h1 = fmaxf(fmaf(bv[i], sc1[k], sh1[k]), 0.f);
            float h2 = fmaxf(fmaf(cv[i], sc2[k], sh2[k]), 0.f);
            float h3 = dv[i] + b3[k];
            at[rr][k] = fmaxf(fmaxf(h1, h2), h3);
        }
    }
    __syncthreads();
    const int c0 = (tid & 15) * 4;
    const int r0 = (tid >> 4) * 4;
    float acc[4][4];
#pragma unroll
    for (int r = 0; r < 4; r++)
#pragma unroll
        for (int c = 0; c < 4; c++) acc[r][c] = 0.0f;
#pragma unroll 4
    for (int k = 0; k < 128; k++) {
        float4 wv = *(const float4*)&Wp[k * 64 + c0];
#pragma unroll
        for (int r = 0; r < 4; r++) {
            float a = at[r0 + r][k];
            acc[r][0] += a * wv.x;
            acc[r][1] += a * wv.y;
            acc[r][2] += a * wv.z;
            acc[r][3] += a * wv.w;
        }
    }
    float4 bpv = *(const float4*)&bp[c0];
#pragma unroll
    for (int r = 0; r < 4; r++) {
        int row = r_base + r0 + r;
        if (row < n) {
            float4 o;
            o.x = acc[r][0] + bpv.x; o.y = acc[r][1] + bpv.y;
            o.z = acc[r][2] + bpv.z; o.w = acc[r][3] + bpv.w;
            *(float4*)&out[(size_t)row * 64 + c0] = o;
        }
    }
}

extern "C" void kernel_launch(void* const* d_in, const int* in_sizes, int n_in,
                              void* d_out, int out_size, void* d_ws, size_t ws_size,
                              hipStream_t stream) {
    const float* x   = (const float*)d_in[0];
    const int*   ei  = (const int*)d_in[1];
    const float* W1  = (const float*)d_in[2];
    // b1 (d_in[3]) cancels inside BatchNorm — skipped
    const float* g1  = (const float*)d_in[4];
    const float* be1 = (const float*)d_in[5];
    const float* W2  = (const float*)d_in[6];
    // b2 (d_in[7]) cancels — skipped
    const float* g2  = (const float*)d_in[8];
    const float* be2 = (const float*)d_in[9];
    const float* W3  = (const float*)d_in[10];
    const float* b3  = (const float*)d_in[11];
    const float* Wp  = (const float*)d_in[12];
    const float* bp  = (const float*)d_in[13];
    float* out = (float*)d_out;

    const int n = in_sizes[0] / F_IN;        // 50000 (< 65536: u16 src packing valid)
    const int e = in_sizes[1] / 2;           // 800000
    const int* src = ei;
    const int* dst = ei + e;
    const int nb = (n + 511) >> 9;           // 98 buckets of 512 nodes (nb <= 128)

    float* ws = (float*)d_ws;
    float*        dinv   = ws;                               // n
    unsigned int* Ab     = (unsigned int*)(ws + n);          // n*64  lin bf16
    unsigned int* Bb     = Ab + (size_t)n * 64;              // n*64  conv1 raw bf16
    unsigned int* Cb     = Bb + (size_t)n * 64;              // n*64  conv2 raw bf16
    unsigned int* Db     = Cb + (size_t)n * 64;              // n*64  conv3 raw bf16
    int*          rowptr = (int*)(Db + (size_t)n * 64);      // n+2
    int*          bstart = rowptr + n + 2;                   // nb+1
    int*          astart = bstart + nb + 1;                  // nb+1
    int*          gtail  = astart + nb + 1;                  // nb
    unsigned*     epack  = (unsigned*)(gtail + nb);          // e
    unsigned*     ebuck  = epack + e;                        // e + 16*(nb+1) staging
    int*          bhs    = (int*)(ebuck + e + 16 * (nb + 1)); // HIST_BLOCKS*128 slices
    float*        sumsL1 = (float*)(bhs + HIST_BLOCKS * 128); // 256 (zeroed in k_hist)
    float*        sumsL2 = sumsL1 + 256;                      // 256 (zeroed in k_hist)
    unsigned*     wfr    = (unsigned*)(sumsL2 + 256);         // 3*8192 bf16 W fragments

    const int BT = 256;
    const int gN  = (n + BT - 1) / BT;                       // 196
    const int gMM = (n + 63) / 64;                           // 782
    const int gG  = (n + 3) / 4;                             // 4 nodes (waves) / block
    const float inv_n = 1.0f / (float)n;

    // ----- W -> MFMA fragment conversion (independent) -----
    k_wconv<<<24, 256, 0, stream>>>(W1, W2, W3, wfr);

    // ----- CSR build: slice hist (also zeroes sums) -> prep -> bin -> place -----
    k_hist<<<HIST_BLOCKS, 256, 0, stream>>>(dst, bhs, sumsL1, e);
    k_prep<<<1, 256, 0, stream>>>(bhs, bstart, astart, gtail, rowptr, nb, n, e);
    k_bin<<<BIN_BLOCKS, 256, 0, stream>>>(src, dst, gtail, ebuck, e, nb);
    k_placeA<<<nb, 256, 0, stream>>>(ebuck, astart, gtail, bstart, rowptr, dinv, n);
    k_placeB<<<nb, 256, 0, stream>>>(ebuck, astart, gtail, bstart, dinv, epack, n);

    // ----- layer 1: lin1 = x@W1 (MFMA) ; aggregate ; stats -----
    k_mm_mfma<0><<<gMM, 256, 0, stream>>>(x, wfr, nullptr, nullptr, nullptr, 0.f, Ab, n);
    k_gather_bf<<<gG, 256, 0, stream>>>(Ab, dinv, rowptr, epack, Bb, n);
    k_colstats_bf<<<gN, 256, 0, stream>>>(Bb, sumsL1, n);

    // ----- layer 2: lin2 = relu(bn1(Bb))@W2 (MFMA) ; aggregate ; stats -----
    k_mm_mfma<1><<<gMM, 256, 0, stream>>>(Bb, wfr + 8192, sumsL1, g1, be1, inv_n, Ab, n);
    k_gather_bf<<<gG, 256, 0, stream>>>(Ab, dinv, rowptr, epack, Cb, n);
    k_colstats_bf<<<gN, 256, 0, stream>>>(Cb, sumsL2, n);

    // ----- layer 3: lin3 = relu(bn2(Cb))@W3 (MFMA) ; aggregate -----
    k_mm_mfma<1><<<gMM, 256, 0, stream>>>(Cb, wfr + 16384, sumsL2, g2, be2, inv_n, Ab, n);
    k_gather_bf<<<gG, 256, 0, stream>>>(Ab, dinv, rowptr, epack, Db, n);

    // ----- JK max + projection -----
    k_jk_final<<<gMM, 256, 0, stream>>>(Bb, Cb, Db, sumsL1, g1, be1, sumsL2, g2, be2,
                                        inv_n, b3, Wp, bp, out, n);
}

// Round 16
// 321.246 us; speedup vs baseline: 1.2436x; 1.0472x over previous
//
#include <hip/hip_runtime.h>

#define F_IN 128
#define H    128
#define OUT  64
#define BN_EPS 1e-5f
#define BIN_BLOCKS 160
#define HIST_BLOCKS 256
#define BUF_CAP 64        // per-bucket LDS staging entries in k_bin
#define OUT_CAP 10240     // per-bucket LDS reorder buffer in k_placeB (40KB)

typedef __attribute__((ext_vector_type(8))) short bf16x8;
typedef __attribute__((ext_vector_type(4))) float f32x4;
union FragU { unsigned u[4]; bf16x8 f; };

// ---------------- bf16 / fp16 helpers ----------------
__device__ inline float bflo(unsigned int v) { return __uint_as_float(v << 16); }
__device__ inline float bfhi(unsigned int v) { return __uint_as_float(v & 0xffff0000u); }
__device__ inline unsigned int pack_bf(float a, float b) {
    unsigned int ua = __float_as_uint(a), ub = __float_as_uint(b);
    ua = (ua + 0x7fffu + ((ua >> 16) & 1u)) >> 16;          // RNE
    ub = (ub + 0x7fffu + ((ub >> 16) & 1u)) >> 16;
    return ua | (ub << 16);
}
union f16u { unsigned short u; _Float16 f; };
__device__ inline unsigned pack_sw(int s, float w) {        // src:u16 | fp16 w:u16
    f16u c; c.f = (_Float16)w;
    return (unsigned)s | ((unsigned)c.u << 16);
}
__device__ inline float unpack_w(unsigned p) {
    f16u c; c.u = (unsigned short)(p >> 16);
    return (float)c.f;
}

// ---------------- bucket histogram: LDS agg -> per-block slice (no global atomics) ----------------
__global__ __launch_bounds__(256) void k_hist(const int* __restrict__ dst, int* bhs,
                                              float* sums_all, int e) {
    __shared__ int h[128];
    const int t = threadIdx.x;
    if (t < 128) h[t] = 0;
    if (blockIdx.x < 2) sums_all[blockIdx.x * 256 + t] = 0.f;
    __syncthreads();
    for (int i = blockIdx.x * 256 + t; i < e; i += gridDim.x * 256)
        atomicAdd(&h[dst[i] >> 9], 1);
    __syncthreads();
    if (t < 128) bhs[blockIdx.x * 128 + t] = h[t];
}

// ---------------- prep: reduce slices -> bucket sizes -> bstart + staging starts ----------------
__global__ __launch_bounds__(256) void k_prep(const int* __restrict__ bhs,
                                              int* bstart, int* astart, int* gtail,
                                              int* rowptr, int nb, int n, int e) {
    __shared__ int part[256];
    __shared__ int bs[128];
    const int t = threadIdx.x;
    const int b = t & 127, half = t >> 7;
    int v = 0;
    for (int s = half * (HIST_BLOCKS / 2); s < (half + 1) * (HIST_BLOCKS / 2); s++)
        v += bhs[s * 128 + b];
    part[t] = v;
    __syncthreads();
    int tot = (t < 128) ? (part[t] + part[t + 128]) : 0;
    if (t < 128) bs[t] = tot;
    __syncthreads();
    for (int off = 1; off < 128; off <<= 1) {
        int x = (t < 128 && t >= off) ? bs[t - off] : 0;
        __syncthreads();
        if (t < 128) bs[t] += x;
        __syncthreads();
    }
    if (t < nb) {
        int excl = bs[t] - tot;                 // exclusive scan
        bstart[t] = excl;
        int a = ((excl + 15) & ~15) + 16 * t;   // 64B-aligned staging start, disjoint
        astart[t] = a;
        gtail[t] = a;
    }
    if (t == 0) { bstart[nb] = e; rowptr[n] = e; }
}

// ---------------- pass 1: LDS-binned scatter to staging (full 64B chunk flushes) ----------------
__global__ __launch_bounds__(256) void k_bin(const int* __restrict__ src, const int* __restrict__ dst,
                                             int* gtail, unsigned* ebuck, int e, int nb) {
    __shared__ unsigned buf[128 * BUF_CAP];  // 32 KB
    __shared__ int cnt[128];
    const int t = threadIdx.x;
    if (t < 128) cnt[t] = 0;
    __syncthreads();
    const int per = (e + gridDim.x - 1) / gridDim.x;
    const int lo = blockIdx.x * per;
    const int hi = min(e, lo + per);
    for (int base = lo; base < hi; base += 1024) {
#pragma unroll
        for (int k = 0; k < 4; k++) {
            int i = base + k * 256 + t;
            if (i < hi) {
                int d = dst[i];
                int b = d >> 9;
                unsigned entry = (unsigned)src[i] | ((unsigned)(d & 511) << 16);
                int slot = atomicAdd(&cnt[b], 1);
                if (slot < BUF_CAP) buf[b * BUF_CAP + slot] = entry;
                else {                               // overflow fallback (never for random input)
                    int pos = atomicAdd(&gtail[b], 1);
                    __builtin_nontemporal_store(entry, &ebuck[pos]);
                }
            }
        }
        __syncthreads();
        if (t < nb) {                                // flush full 16-entry chunks
            int c = cnt[t]; if (c > BUF_CAP) c = BUF_CAP;
            int full = c & ~15;
            if (full > 0) {
                int bp = atomicAdd(&gtail[t], full);
                for (int j = 0; j < full; j++)
                    __builtin_nontemporal_store(buf[t * BUF_CAP + j], &ebuck[bp + j]);
                int rem = c - full;
                for (int j = 0; j < rem; j++) buf[t * BUF_CAP + j] = buf[t * BUF_CAP + full + j];
                cnt[t] = rem;
            }
        }
        __syncthreads();
    }
    if (t < nb) {                                    // final drain (partial)
        int c = cnt[t]; if (c > BUF_CAP) c = BUF_CAP;
        if (c > 0) {
            int bp = atomicAdd(&gtail[t], c);
            for (int j = 0; j < c; j++)
                __builtin_nontemporal_store(buf[t * BUF_CAP + j], &ebuck[bp + j]);
        }
    }
}

// ---------------- pass 2a: per-bucket hist -> rowptr + dinv + exported exclusive scan ----------------
__global__ __launch_bounds__(256) void k_placeA(const unsigned* __restrict__ ebuck,
                                                const int* __restrict__ astart,
                                                const int* __restrict__ gtail,
                                                const int* __restrict__ bstart,
                                                int* rowptr, float* dinv, int* sexc, int n) {
    __shared__ int hist[512];
    __shared__ int scn[512];
    const int b = blockIdx.x, t = threadIdx.x;
    hist[t] = 0; hist[t + 256] = 0;
    __syncthreads();
    const int s0 = astart[b], s1 = gtail[b];
    for (int i = s0 + t; i < s1; i += 256) atomicAdd(&hist[ebuck[i] >> 16], 1);
    __syncthreads();
    scn[t] = hist[t]; scn[t + 256] = hist[t + 256];
    __syncthreads();
    for (int off = 1; off < 512; off <<= 1) {
        int a = (t >= off) ? scn[t - off] : 0;
        int c = (t + 256 >= off) ? scn[t + 256 - off] : 0;
        __syncthreads();
        scn[t] += a; scn[t + 256] += c;
        __syncthreads();
    }
    const int nodebase = b << 9;
    const int base = bstart[b];
    int e0 = scn[t] - hist[t];                 // exclusive within bucket
    int e1 = scn[t + 256] - hist[t + 256];
    sexc[b * 512 + t]       = e0;              // handoff to placeB
    sexc[b * 512 + t + 256] = e1;
    int node = nodebase + t;
    if (node < n) { rowptr[node] = base + e0; dinv[node] = rsqrtf((float)(hist[t] + 1)); }
    node = nodebase + 256 + t;
    if (node < n) { rowptr[node] = base + e1; dinv[node] = rsqrtf((float)(hist[t + 256] + 1)); }
}

// ---------------- pass 2b: LDS reorder -> coalesced final epack (scan reused from placeA) ----------------
__global__ __launch_bounds__(256) void k_placeB(const unsigned* __restrict__ ebuck,
                                                const int* __restrict__ astart,
                                                const int* __restrict__ gtail,
                                                const int* __restrict__ bstart,
                                                const int* __restrict__ sexc,
                                                const float* __restrict__ dinv,
                                                unsigned* epack, int n) {
    __shared__ int hist[512];
    __shared__ int scn[512];
    __shared__ float dloc[512];
    __shared__ unsigned outb[OUT_CAP];       // 40 KB
    const int b = blockIdx.x, t = threadIdx.x;
    const int nodebase = b << 9;
    hist[t] = 0; hist[t + 256] = 0;
    scn[t]       = sexc[b * 512 + t];
    scn[t + 256] = sexc[b * 512 + t + 256];
    dloc[t]       = (nodebase + t       < n) ? dinv[nodebase + t]       : 0.f;
    dloc[t + 256] = (nodebase + 256 + t < n) ? dinv[nodebase + 256 + t] : 0.f;
    __syncthreads();
    const int s0 = astart[b], s1 = gtail[b];
    const int base = bstart[b];
    for (int i = s0 + t; i < s1; i += 256) {
        unsigned en = ebuck[i];
        int dlow = en >> 16;
        int s = en & 0xffffu;
        int pos = scn[dlow] + atomicAdd(&hist[dlow], 1);
        unsigned word = pack_sw(s, dinv[s] * dloc[dlow]);
        if (pos < OUT_CAP) outb[pos] = word;
        else __builtin_nontemporal_store(word, &epack[base + pos]);   // overflow fallback
    }
    __syncthreads();
    int total = s1 - s0; if (total > OUT_CAP) total = OUT_CAP;
    for (int j = t; j < total; j += 256) epack[base + j] = outb[j];
}

// ---------------- W -> bf16 MFMA B-fragment conversion (W1/W2/W3 + Wp) ----------------
__global__ __launch_bounds__(256) void k_wconv(const float* __restrict__ W1,
                                               const float* __restrict__ W2,
                                               const float* __restrict__ W3,
                                               const float* __restrict__ Wp,
                                               unsigned* __restrict__ wf) {
    int t = blockIdx.x * 256 + threadIdx.x;      // 0..7167
    if (t < 6144) {
        int w = t >> 11;
        int rem = t & 2047;
        int ks = rem >> 9;
        int ct = (rem >> 6) & 7;
        int lane = rem & 63;
        const float* W = (w == 0) ? W1 : (w == 1) ? W2 : W3;
        int col = ct * 16 + (lane & 15);
        int kb = ks * 32 + (lane >> 4) * 8;
        uint4 pk;
        pk.x = pack_bf(W[(kb + 0) * 128 + col], W[(kb + 1) * 128 + col]);
        pk.y = pack_bf(W[(kb + 2) * 128 + col], W[(kb + 3) * 128 + col]);
        pk.z = pack_bf(W[(kb + 4) * 128 + col], W[(kb + 5) * 128 + col]);
        pk.w = pack_bf(W[(kb + 6) * 128 + col], W[(kb + 7) * 128 + col]);
        ((uint4*)(wf + (size_t)w * 8192))[(ks * 8 + ct) * 64 + lane] = pk;
    } else if (t < 7168) {
        int rem = t - 6144;                      // Wp: 128x64
        int ks = rem >> 8;                       // 4 k-steps
        int ct = (rem >> 6) & 3;                 // 4 col-tiles
        int lane = rem & 63;
        int col = ct * 16 + (lane & 15);
        int kb = ks * 32 + (lane >> 4) * 8;
        uint4 pk;
        pk.x = pack_bf(Wp[(kb + 0) * 64 + col], Wp[(kb + 1) * 64 + col]);
        pk.y = pack_bf(Wp[(kb + 2) * 64 + col], Wp[(kb + 3) * 64 + col]);
        pk.z = pack_bf(Wp[(kb + 4) * 64 + col], Wp[(kb + 5) * 64 + col]);
        pk.w = pack_bf(Wp[(kb + 6) * 64 + col], Wp[(kb + 7) * 64 + col]);
        ((uint4*)(wf + 24576))[(ks * 4 + ct) * 64 + lane] = pk;
    }
}

// derive BN scale/shift from sums into LDS
__device__ inline void bn_to_lds(const float* __restrict__ sums, const float* __restrict__ g,
                                 const float* __restrict__ be, float* sc_s, float* sh_s,
                                 float inv_n, int tid) {
    if (tid < 128) {
        float m  = sums[tid] * inv_n;
        float v  = sums[128 + tid] * inv_n - m * m;
        float rs = rsqrtf(v + BN_EPS);
        float s  = g[tid] * rs;
        sc_s[tid] = s;
        sh_s[tid] = be[tid] - m * s;
    }
}

// ---------------- MFMA GEMM: C[n x 128] = act(A) @ W -> packed bf16 ----------------
template<int MODE>
__global__ __launch_bounds__(256) void k_mm_mfma(const void* __restrict__ Aptr,
                                                 const unsigned* __restrict__ wfrag,
                                                 const float* __restrict__ sums,
                                                 const float* __restrict__ g,
                                                 const float* __restrict__ be, float inv_n,
                                                 unsigned* __restrict__ outb, int n) {
    __shared__ float sc_s[128], sh_s[128];
    __shared__ float dtile[4][16][130];
    const int tid = threadIdx.x;
    if (MODE == 1) {
        bn_to_lds(sums, g, be, sc_s, sh_s, inv_n, tid);
        __syncthreads();
    }
    const int wave = tid >> 6, lane = tid & 63;
    const int r0 = blockIdx.x * 64 + wave * 16;
    const int arow = r0 + (lane & 15);
    const int koff = (lane >> 4) * 8;

    FragU afr[4];
    if (MODE == 0) {
        const float* A = (const float*)Aptr;
#pragma unroll
        for (int ks = 0; ks < 4; ks++) {
            float4 v0 = make_float4(0.f, 0.f, 0.f, 0.f), v1 = v0;
            if (arow < n) {
                v0 = *(const float4*)&A[(size_t)arow * 128 + ks * 32 + koff];
                v1 = *(const float4*)&A[(size_t)arow * 128 + ks * 32 + koff + 4];
            }
            afr[ks].u[0] = pack_bf(v0.x, v0.y);
            afr[ks].u[1] = pack_bf(v0.z, v0.w);
            afr[ks].u[2] = pack_bf(v1.x, v1.y);
            afr[ks].u[3] = pack_bf(v1.z, v1.w);
        }
    } else {
        const unsigned* Ab = (const unsigned*)Aptr;
#pragma unroll
        for (int ks = 0; ks < 4; ks++) {
            uint4 v = make_uint4(0u, 0u, 0u, 0u);
            if (arow < n) v = *(const uint4*)&Ab[(size_t)arow * 64 + ks * 16 + (lane >> 4) * 4];
            unsigned vv[4] = {v.x, v.y, v.z, v.w};
            const int kk = ks * 32 + koff;
#pragma unroll
            for (int q = 0; q < 4; q++) {
                int k0 = kk + 2 * q;
                float lo = fmaxf(fmaf(bflo(vv[q]), sc_s[k0],     sh_s[k0]),     0.f);
                float hi = fmaxf(fmaf(bfhi(vv[q]), sc_s[k0 + 1], sh_s[k0 + 1]), 0.f);
                afr[ks].u[q] = pack_bf(lo, hi);
            }
        }
    }

    const uint4* wf4 = (const uint4*)wfrag;
    const int drow = (lane >> 4) * 4;
#pragma unroll
    for (int ct = 0; ct < 8; ct++) {
        f32x4 acc = {0.f, 0.f, 0.f, 0.f};
#pragma unroll
        for (int ks = 0; ks < 4; ks++) {
            FragU b;
            *(uint4*)b.u = wf4[(ks * 8 + ct) * 64 + lane];
            acc = __builtin_amdgcn_mfma_f32_16x16x32_bf16(afr[ks].f, b.f, acc, 0, 0, 0);
        }
        const int dcol = ct * 16 + (lane & 15);
#pragma unroll
        for (int r = 0; r < 4; r++) dtile[wave][drow + r][dcol] = acc[r];
    }
    // wave-private transpose readback
    const int lr = lane >> 2;
    const int uc = (lane & 3) * 16;
    if (r0 + lr < n) {
#pragma unroll
        for (int q2 = 0; q2 < 4; q2++) {
            const float* s = &dtile[wave][lr][2 * uc + 8 * q2];
            uint4 pk;
            pk.x = pack_bf(s[0], s[1]);
            pk.y = pack_bf(s[2], s[3]);
            pk.z = pack_bf(s[4], s[5]);
            pk.w = pack_bf(s[6], s[7]);
            *(uint4*)&outb[(size_t)(r0 + lr) * 64 + uc + 4 * q2] = pk;
        }
    }
}

// ---------------- JK max (BN'd, 3-way) + MFMA projection -> fp32 out ----------------
__global__ __launch_bounds__(256) void k_jk_mfma(const unsigned* __restrict__ Bb,
                                                 const unsigned* __restrict__ Cb,
                                                 const unsigned* __restrict__ Db,
                                                 const unsigned* __restrict__ wpf,
                                                 const float* __restrict__ sumsL1,
                                                 const float* __restrict__ g1, const float* __restrict__ be1,
                                                 const float* __restrict__ sumsL2,
                                                 const float* __restrict__ g2, const float* __restrict__ be2,
                                                 float inv_n,
                                                 const float* __restrict__ b3,
                                                 const float* __restrict__ bp,
                                                 float* __restrict__ out, int n) {
    __shared__ float sc1[128], sh1[128], sc2[128], sh2[128];
    __shared__ float dtile[4][16][68];
    const int tid = threadIdx.x;
    bn_to_lds(sumsL1, g1, be1, sc1, sh1, inv_n, tid);
    bn_to_lds(sumsL2, g2, be2, sc2, sh2, inv_n, tid);
    __syncthreads();
    const int wave = tid >> 6, lane = tid & 63;
    const int r0 = blockIdx.x * 64 + wave * 16;
    const int arow = r0 + (lane & 15);
    const int koff = (lane >> 4) * 8;

    FragU afr[4];
#pragma unroll
    for (int ks = 0; ks < 4; ks++) {
        uint4 vb = make_uint4(0u,0u,0u,0u), vc = vb, vd = vb;
        if (arow < n) {
            size_t gi = (size_t)arow * 64 + ks * 16 + (lane >> 4) * 4;
            vb = *(const uint4*)&Bb[gi];
            vc = *(const uint4*)&Cb[gi];
            vd = *(const uint4*)&Db[gi];
        }
        unsigned bu[4] = {vb.x, vb.y, vb.z, vb.w};
        unsigned cu[4] = {vc.x, vc.y, vc.z, vc.w};
        unsigned du[4] = {vd.x, vd.y, vd.z, vd.w};
        const int kk = ks * 32 + koff;
#pragma unroll
        for (int q = 0; q < 4; q++) {
            int k0 = kk + 2 * q;
            float h1a = fmaxf(fmaf(bflo(bu[q]), sc1[k0],     sh1[k0]),     0.f);
            float h1b = fmaxf(fmaf(bfhi(bu[q]), sc1[k0 + 1], sh1[k0 + 1]), 0.f);
            float h2a = fmaxf(fmaf(bflo(cu[q]), sc2[k0],     sh2[k0]),     0.f);
            float h2b = fmaxf(fmaf(bfhi(cu[q]), sc2[k0 + 1], sh2[k0 + 1]), 0.f);
            float h3a = bflo(du[q]) + b3[k0];
            float h3b = bfhi(du[q]) + b3[k0 + 1];
            afr[ks].u[q] = pack_bf(fmaxf(fmaxf(h1a, h2a), h3a),
                                   fmaxf(fmaxf(h1b, h2b), h3b));
        }
    }

    const uint4* wf4 = (const uint4*)wpf;
    const int drow = (lane >> 4) * 4;
#pragma unroll
    for (int ct = 0; ct < 4; ct++) {
        f32x4 acc = {0.f, 0.f, 0.f, 0.f};
#pragma unroll
        for (int ks = 0; ks < 4; ks++) {
            FragU b;
            *(uint4*)b.u = wf4[(ks * 4 + ct) * 64 + lane];
            acc = __builtin_amdgcn_mfma_f32_16x16x32_bf16(afr[ks].f, b.f, acc, 0, 0, 0);
        }
        const int dcol = ct * 16 + (lane & 15);
        const float bb = bp[dcol];
#pragma unroll
        for (int r = 0; r < 4; r++) dtile[wave][drow + r][dcol] = acc[r] + bb;
    }
    // wave-private transpose readback -> fp32 out
    const int lr = lane >> 2;
    const int uc = (lane & 3) * 16;
    if (r0 + lr < n) {
#pragma unroll
        for (int q2 = 0; q2 < 4; q2++) {
            *(float4*)&out[(size_t)(r0 + lr) * 64 + uc + 4 * q2] =
                *(const float4*)&dtile[wave][lr][uc + 4 * q2];
        }
    }
}

// ---------------- pull aggregation: 64 lanes/node, 16-deep then 8-deep unroll ----------------
__global__ __launch_bounds__(256) void k_gather_bf(const unsigned int* __restrict__ linb,
                                                   const float* __restrict__ dinv,
                                                   const int* __restrict__ rowptr,
                                                   const unsigned* __restrict__ epack,
                                                   unsigned int* __restrict__ outb, int n) {
    const int t = threadIdx.x & 63;                          // feats 2t, 2t+1
    int node = blockIdx.x * 4 + (threadIdx.x >> 6);
    if (node >= n) return;
    node = __builtin_amdgcn_readfirstlane(node);
    const float dd = dinv[node];
    int p0 = rowptr[node];
    int p1 = rowptr[node + 1];
    p0 = __builtin_amdgcn_readfirstlane(p0);
    p1 = __builtin_amdgcn_readfirstlane(p1);

    float a0 = 0.f, a1 = 0.f, b0 = 0.f, b1 = 0.f;
    float c0 = 0.f, c1 = 0.f, d0 = 0.f, d1 = 0.f;
    int p = p0;
    for (; p + 16 <= p1; p += 16) {
        unsigned ee[16];
#pragma unroll
        for (int j = 0; j < 16; j++) ee[j] = epack[p + j];
        unsigned vv[16];
#pragma unroll
        for (int j = 0; j < 16; j++) vv[j] = linb[(size_t)(ee[j] & 0xffffu) * 64 + t];
#pragma unroll
        for (int j = 0; j < 16; j += 4) {
            float w0 = unpack_w(ee[j]), w1 = unpack_w(ee[j+1]);
            float w2 = unpack_w(ee[j+2]), w3 = unpack_w(ee[j+3]);
            a0 += bflo(vv[j])   * w0; a1 += bfhi(vv[j])   * w0;
            b0 += bflo(vv[j+1]) * w1; b1 += bfhi(vv[j+1]) * w1;
            c0 += bflo(vv[j+2]) * w2; c1 += bfhi(vv[j+2]) * w2;
            d0 += bflo(vv[j+3]) * w3; d1 += bfhi(vv[j+3]) * w3;
        }
    }
    for (; p + 8 <= p1; p += 8) {
        unsigned e0 = epack[p+0], e1 = epack[p+1], e2 = epack[p+2], e3 = epack[p+3];
        unsigned e4 = epack[p+4], e5 = epack[p+5], e6 = epack[p+6], e7 = epack[p+7];
        unsigned v0 = linb[(size_t)(e0 & 0xffffu) * 64 + t];
        unsigned v1 = linb[(size_t)(e1 & 0xffffu) * 64 + t];
        unsigned v2 = linb[(size_t)(e2 & 0xffffu) * 64 + t];
        unsigned v3 = linb[(size_t)(e3 & 0xffffu) * 64 + t];
        unsigned v4 = linb[(size_t)(e4 & 0xffffu) * 64 + t];
        unsigned v5 = linb[(size_t)(e5 & 0xffffu) * 64 + t];
        unsigned v6 = linb[(size_t)(e6 & 0xffffu) * 64 + t];
        unsigned v7 = linb[(size_t)(e7 & 0xffffu) * 64 + t];
        float w0 = unpack_w(e0), w1 = unpack_w(e1), w2 = unpack_w(e2), w3 = unpack_w(e3);
        float w4 = unpack_w(e4), w5 = unpack_w(e5), w6 = unpack_w(e6), w7 = unpack_w(e7);
        a0 += bflo(v0) * w0; a1 += bfhi(v0) * w0;
        b0 += bflo(v1) * w1; b1 += bfhi(v1) * w1;
        c0 += bflo(v2) * w2; c1 += bfhi(v2) * w2;
        d0 += bflo(v3) * w3; d1 += bfhi(v3) * w3;
        a0 += bflo(v4) * w4; a1 += bfhi(v4) * w4;
        b0 += bflo(v5) * w5; b1 += bfhi(v5) * w5;
        c0 += bflo(v6) * w6; c1 += bfhi(v6) * w6;
        d0 += bflo(v7) * w7; d1 += bfhi(v7) * w7;
    }
    for (; p < p1; p++) {
        unsigned ep = epack[p];
        unsigned v = linb[(size_t)(ep & 0xffffu) * 64 + t];
        float w = unpack_w(ep);
        a0 += bflo(v) * w; a1 += bfhi(v) * w;
    }
    {   // self-loop
        unsigned vs = linb[(size_t)node * 64 + t];
        float wsl = dd * dd;
        a0 += bflo(vs) * wsl; a1 += bfhi(vs) * wsl;
    }
    float F0 = (a0 + b0) + (c0 + d0);
    float F1 = (a1 + b1) + (c1 + d1);
    outb[(size_t)node * 64 + t] = pack_bf(F0, F1);
}

// ---------------- column stats from bf16 rows ----------------
__global__ __launch_bounds__(256) void k_colstats_bf(const unsigned int* __restrict__ hb,
                                                     float* sums, int n) {
    __shared__ float red[4][4][64];          // {slo,shi,qlo,qhi}[sub][t]
    int t = threadIdx.x & 63, sub = threadIdx.x >> 6;
    int r1 = min(blockIdx.x * 256 + 256, n);
    float s0 = 0.f, s1 = 0.f, q0 = 0.f, q1 = 0.f;
    for (int r = blockIdx.x * 256 + sub; r < r1; r += 4) {
        unsigned int v = hb[(size_t)r * 64 + t];
        float a = bflo(v), b = bfhi(v);
        s0 += a; q0 += a * a;
        s1 += b; q1 += b * b;
    }
    red[0][sub][t] = s0; red[1][sub][t] = s1;
    red[2][sub][t] = q0; red[3][sub][t] = q1;
    __syncthreads();
    if (sub == 0) {
        float ts0 = red[0][0][t] + red[0][1][t] + red[0][2][t] + red[0][3][t];
        float ts1 = red[1][0][t] + red[1][1][t] + red[1][2][t] + red[1][3][t];
        float tq0 = red[2][0][t] + red[2][1][t] + red[2][2][t] + red[2][3][t];
        float tq1 = red[3][0][t] + red[3][1][t] + red[3][2][t] + red[3][3][t];
        atomicAdd(&sums[2 * t],           ts0);
        atomicAdd(&sums[2 * t + 1],       ts1);
        atomicAdd(&sums[128 + 2 * t],     tq0);
        atomicAdd(&sums[128 + 2 * t + 1], tq1);
    }
}

extern "C" void kernel_launch(void* const* d_in, const int* in_sizes, int n_in,
                              void* d_out, int out_size, void* d_ws, size_t ws_size,
                              hipStream_t stream) {
    const float* x   = (const float*)d_in[0];
    const int*   ei  = (const int*)d_in[1];
    const float* W1  = (const float*)d_in[2];
    // b1 (d_in[3]) cancels inside BatchNorm — skipped
    const float* g1  = (const float*)d_in[4];
    const float* be1 = (const float*)d_in[5];
    const float* W2  = (const float*)d_in[6];
    // b2 (d_in[7]) cancels — skipped
    const float* g2  = (const float*)d_in[8];
    const float* be2 = (const float*)d_in[9];
    const float* W3  = (const float*)d_in[10];
    const float* b3  = (const float*)d_in[11];
    const float* Wp  = (const float*)d_in[12];
    const float* bp  = (const float*)d_in[13];
    float* out = (float*)d_out;

    const int n = in_sizes[0] / F_IN;        // 50000 (< 65536: u16 src packing valid)
    const int e = in_sizes[1] / 2;           // 800000
    const int* src = ei;
    const int* dst = ei + e;
    const int nb = (n + 511) >> 9;           // 98 buckets of 512 nodes (nb <= 128)

    float* ws = (float*)d_ws;
    float*        dinv   = ws;                               // n
    unsigned int* Ab     = (unsigned int*)(ws + n);          // n*64  lin bf16
    unsigned int* Bb     = Ab + (size_t)n * 64;              // n*64  conv1 raw bf16
    unsigned int* Cb     = Bb + (size_t)n * 64;              // n*64  conv2 raw bf16
    unsigned int* Db     = Cb + (size_t)n * 64;              // n*64  conv3 raw bf16
    int*          rowptr = (int*)(Db + (size_t)n * 64);      // n+2
    int*          bstart = rowptr + n + 2;                   // nb+1
    int*          astart = bstart + nb + 1;                  // nb+1
    int*          gtail  = astart + nb + 1;                  // nb
    unsigned*     epack  = (unsigned*)(gtail + nb);          // e
    unsigned*     ebuck  = epack + e;                        // e + 16*(nb+1) staging
    int*          bhs    = (int*)(ebuck + e + 16 * (nb + 1)); // HIST_BLOCKS*128 slices
    int*          sexc   = bhs + HIST_BLOCKS * 128;          // nb*512 scan handoff
    float*        sumsL1 = (float*)(sexc + nb * 512);        // 256 (zeroed in k_hist)
    float*        sumsL2 = sumsL1 + 256;                     // 256 (zeroed in k_hist)
    unsigned*     wfr    = (unsigned*)(sumsL2 + 256);        // 3*8192 + 4096 bf16 W fragments

    const int BT = 256;
    const int gN  = (n + BT - 1) / BT;                       // 196
    const int gMM = (n + 63) / 64;                           // 782
    const int gG  = (n + 3) / 4;                             // 4 nodes (waves) / block
    const float inv_n = 1.0f / (float)n;

    // ----- W -> MFMA fragment conversion (independent) -----
    k_wconv<<<28, 256, 0, stream>>>(W1, W2, W3, Wp, wfr);

    // ----- CSR build: slice hist (also zeroes sums) -> prep -> bin -> place -----
    k_hist<<<HIST_BLOCKS, 256, 0, stream>>>(dst, bhs, sumsL1, e);
    k_prep<<<1, 256, 0, stream>>>(bhs, bstart, astart, gtail, rowptr, nb, n, e);
    k_bin<<<BIN_BLOCKS, 256, 0, stream>>>(src, dst, gtail, ebuck, e, nb);
    k_placeA<<<nb, 256, 0, stream>>>(ebuck, astart, gtail, bstart, rowptr, dinv, sexc, n);
    k_placeB<<<nb, 256, 0, stream>>>(ebuck, astart, gtail, bstart, sexc, dinv, epack, n);

    // ----- layer 1: lin1 = x@W1 (MFMA) ; aggregate ; stats -----
    k_mm_mfma<0><<<gMM, 256, 0, stream>>>(x, wfr, nullptr, nullptr, nullptr, 0.f, Ab, n);
    k_gather_bf<<<gG, 256, 0, stream>>>(Ab, dinv, rowptr, epack, Bb, n);
    k_colstats_bf<<<gN, 256, 0, stream>>>(Bb, sumsL1, n);

    // ----- layer 2: lin2 = relu(bn1(Bb))@W2 (MFMA) ; aggregate ; stats -----
    k_mm_mfma<1><<<gMM, 256, 0, stream>>>(Bb, wfr + 8192, sumsL1, g1, be1, inv_n, Ab, n);
    k_gather_bf<<<gG, 256, 0, stream>>>(Ab, dinv, rowptr, epack, Cb, n);
    k_colstats_bf<<<gN, 256, 0, stream>>>(Cb, sumsL2, n);

    // ----- layer 3: lin3 = relu(bn2(Cb))@W3 (MFMA) ; aggregate -----
    k_mm_mfma<1><<<gMM, 256, 0, stream>>>(Cb, wfr + 16384, sumsL2, g2, be2, inv_n, Ab, n);
    k_gather_bf<<<gG, 256, 0, stream>>>(Ab, dinv, rowptr, epack, Db, n);

    // ----- JK max + MFMA projection -----
    k_jk_mfma<<<gMM, 256, 0, stream>>>(Bb, Cb, Db, wfr + 24576,
                                       sumsL1, g1, be1, sumsL2, g2, be2,
                                       inv_n, b3, bp, out, n);
}

// Round 18
// 315.141 us; speedup vs baseline: 1.2677x; 1.0194x over previous
//
#include <hip/hip_runtime.h>

#define F_IN 128
#define H    128
#define OUT  64
#define BN_EPS 1e-5f
#define BIN_BLOCKS 160
#define HIST_BLOCKS 256
#define WCONV_BLOCKS 28
#define BUF_CAP 64        // per-bucket LDS staging entries in k_bin
#define OUT_CAP 10240     // per-bucket LDS reorder buffer in k_placeB (40KB)

typedef __attribute__((ext_vector_type(8))) short bf16x8;
typedef __attribute__((ext_vector_type(4))) float f32x4;
typedef __attribute__((ext_vector_type(4))) unsigned uint32x4;   // native vec for NT stores
union FragU { unsigned u[4]; bf16x8 f; };

// ---------------- bf16 / fp16 helpers ----------------
__device__ inline float bflo(unsigned int v) { return __uint_as_float(v << 16); }
__device__ inline float bfhi(unsigned int v) { return __uint_as_float(v & 0xffff0000u); }
__device__ inline unsigned int pack_bf(float a, float b) {
    unsigned int ua = __float_as_uint(a), ub = __float_as_uint(b);
    ua = (ua + 0x7fffu + ((ua >> 16) & 1u)) >> 16;          // RNE
    ub = (ub + 0x7fffu + ((ub >> 16) & 1u)) >> 16;
    return ua | (ub << 16);
}
union f16u { unsigned short u; _Float16 f; };
__device__ inline unsigned pack_sw(int s, float w) {        // src:u16 | fp16 w:u16
    f16u c; c.f = (_Float16)w;
    return (unsigned)s | ((unsigned)c.u << 16);
}
__device__ inline float unpack_w(unsigned p) {
    f16u c; c.u = (unsigned short)(p >> 16);
    return (float)c.f;
}

// ---------------- merged: bucket histogram (blocks < HIST_BLOCKS) || W-fragment conv ----------------
__global__ __launch_bounds__(256) void k_histw(const int* __restrict__ dst, int* bhs,
                                               float* sums_all, int e,
                                               const float* __restrict__ W1,
                                               const float* __restrict__ W2,
                                               const float* __restrict__ W3,
                                               const float* __restrict__ Wp,
                                               unsigned* __restrict__ wf) {
    __shared__ int h[128];
    const int t = threadIdx.x;
    if (blockIdx.x < HIST_BLOCKS) {
        if (t < 128) h[t] = 0;
        if (blockIdx.x < 2) sums_all[blockIdx.x * 256 + t] = 0.f;
        __syncthreads();
        for (int i = blockIdx.x * 256 + t; i < e; i += HIST_BLOCKS * 256)
            atomicAdd(&h[dst[i] >> 9], 1);
        __syncthreads();
        if (t < 128) bhs[blockIdx.x * 128 + t] = h[t];
        return;
    }
    // ---- W fragment conversion ----
    int g = (blockIdx.x - HIST_BLOCKS) * 256 + t;            // 0..7167
    if (g < 6144) {
        int w = g >> 11;
        int rem = g & 2047;
        int ks = rem >> 9;
        int ct = (rem >> 6) & 7;
        int lane = rem & 63;
        const float* W = (w == 0) ? W1 : (w == 1) ? W2 : W3;
        int col = ct * 16 + (lane & 15);
        int kb = ks * 32 + (lane >> 4) * 8;
        uint4 pk;
        pk.x = pack_bf(W[(kb + 0) * 128 + col], W[(kb + 1) * 128 + col]);
        pk.y = pack_bf(W[(kb + 2) * 128 + col], W[(kb + 3) * 128 + col]);
        pk.z = pack_bf(W[(kb + 4) * 128 + col], W[(kb + 5) * 128 + col]);
        pk.w = pack_bf(W[(kb + 6) * 128 + col], W[(kb + 7) * 128 + col]);
        ((uint4*)(wf + (size_t)w * 8192))[(ks * 8 + ct) * 64 + lane] = pk;
    } else if (g < 7168) {
        int rem = g - 6144;                      // Wp: 128x64
        int ks = rem >> 8;
        int ct = (rem >> 6) & 3;
        int lane = rem & 63;
        int col = ct * 16 + (lane & 15);
        int kb = ks * 32 + (lane >> 4) * 8;
        uint4 pk;
        pk.x = pack_bf(Wp[(kb + 0) * 64 + col], Wp[(kb + 1) * 64 + col]);
        pk.y = pack_bf(Wp[(kb + 2) * 64 + col], Wp[(kb + 3) * 64 + col]);
        pk.z = pack_bf(Wp[(kb + 4) * 64 + col], Wp[(kb + 5) * 64 + col]);
        pk.w = pack_bf(Wp[(kb + 6) * 64 + col], Wp[(kb + 7) * 64 + col]);
        ((uint4*)(wf + 24576))[(ks * 4 + ct) * 64 + lane] = pk;
    }
}

// ---------------- prep: reduce slices -> bucket sizes -> bstart + staging starts ----------------
__global__ __launch_bounds__(256) void k_prep(const int* __restrict__ bhs,
                                              int* bstart, int* astart, int* gtail,
                                              int* rowptr, int nb, int n, int e) {
    __shared__ int part[256];
    __shared__ int bs[128];
    const int t = threadIdx.x;
    const int b = t & 127, half = t >> 7;
    int v = 0;
    for (int s = half * (HIST_BLOCKS / 2); s < (half + 1) * (HIST_BLOCKS / 2); s++)
        v += bhs[s * 128 + b];
    part[t] = v;
    __syncthreads();
    int tot = (t < 128) ? (part[t] + part[t + 128]) : 0;
    if (t < 128) bs[t] = tot;
    __syncthreads();
    for (int off = 1; off < 128; off <<= 1) {
        int x = (t < 128 && t >= off) ? bs[t - off] : 0;
        __syncthreads();
        if (t < 128) bs[t] += x;
        __syncthreads();
    }
    if (t < nb) {
        int excl = bs[t] - tot;                 // exclusive scan
        bstart[t] = excl;
        int a = ((excl + 15) & ~15) + 16 * t;   // 64B-aligned staging start, disjoint
        astart[t] = a;
        gtail[t] = a;
    }
    if (t == 0) { bstart[nb] = e; rowptr[n] = e; }
}

// ---------------- pass 1: LDS-binned scatter to staging (uint32x4 NT flushes) ----------------
// gtail starts 16-word aligned; chunk flushes advance by multiples of 16 -> bp stays 16-aligned.
__global__ __launch_bounds__(256) void k_bin(const int* __restrict__ src, const int* __restrict__ dst,
                                             int* gtail, unsigned* ebuck, int e, int nb) {
    __shared__ unsigned buf[128 * BUF_CAP];  // 32 KB
    __shared__ int cnt[128];
    const int t = threadIdx.x;
    if (t < 128) cnt[t] = 0;
    __syncthreads();
    const int per = (e + gridDim.x - 1) / gridDim.x;
    const int lo = blockIdx.x * per;
    const int hi = min(e, lo + per);
    for (int base = lo; base < hi; base += 1024) {
#pragma unroll
        for (int k = 0; k < 4; k++) {
            int i = base + k * 256 + t;
            if (i < hi) {
                int d = dst[i];
                int b = d >> 9;
                unsigned entry = (unsigned)src[i] | ((unsigned)(d & 511) << 16);
                int slot = atomicAdd(&cnt[b], 1);
                if (slot < BUF_CAP) buf[b * BUF_CAP + slot] = entry;
                else {                               // overflow fallback (never for random input)
                    int pos = atomicAdd(&gtail[b], 1);
                    __builtin_nontemporal_store(entry, &ebuck[pos]);
                }
            }
        }
        __syncthreads();
        if (t < nb) {                                // flush full 16-entry chunks as uint32x4
            int c = cnt[t]; if (c > BUF_CAP) c = BUF_CAP;
            int full = c & ~15;
            if (full > 0) {
                int bp = atomicAdd(&gtail[t], full);
                uint32x4* dst4 = (uint32x4*)&ebuck[bp];
                const uint32x4* src4 = (const uint32x4*)&buf[t * BUF_CAP];
                for (int j4 = 0; j4 < (full >> 2); j4++)
                    __builtin_nontemporal_store(src4[j4], &dst4[j4]);
                int rem = c - full;
                for (int j = 0; j < rem; j++) buf[t * BUF_CAP + j] = buf[t * BUF_CAP + full + j];
                cnt[t] = rem;
            }
        }
        __syncthreads();
    }
    if (t < nb) {                                    // final drain (vec quads + word tail)
        int c = cnt[t]; if (c > BUF_CAP) c = BUF_CAP;
        if (c > 0) {
            int bp = atomicAdd(&gtail[t], c);        // bp 16-aligned here (all prior bumps x16)
            int q = c >> 2;
            uint32x4* dst4 = (uint32x4*)&ebuck[bp];
            const uint32x4* src4 = (const uint32x4*)&buf[t * BUF_CAP];
            for (int j4 = 0; j4 < q; j4++)
                __builtin_nontemporal_store(src4[j4], &dst4[j4]);
            for (int j = q << 2; j < c; j++)
                __builtin_nontemporal_store(buf[t * BUF_CAP + j], &ebuck[bp + j]);
        }
    }
}

// ---------------- pass 2a: per-bucket hist -> rowptr + dinv + exported exclusive scan ----------------
__global__ __launch_bounds__(256) void k_placeA(const unsigned* __restrict__ ebuck,
                                                const int* __restrict__ astart,
                                                const int* __restrict__ gtail,
                                                const int* __restrict__ bstart,
                                                int* rowptr, float* dinv, int* sexc, int n) {
    __shared__ int hist[512];
    __shared__ int scn[512];
    const int b = blockIdx.x, t = threadIdx.x;
    hist[t] = 0; hist[t + 256] = 0;
    __syncthreads();
    const int s0 = astart[b], s1 = gtail[b];
    for (int i = s0 + t; i < s1; i += 256) atomicAdd(&hist[ebuck[i] >> 16], 1);
    __syncthreads();
    scn[t] = hist[t]; scn[t + 256] = hist[t + 256];
    __syncthreads();
    for (int off = 1; off < 512; off <<= 1) {
        int a = (t >= off) ? scn[t - off] : 0;
        int c = (t + 256 >= off) ? scn[t + 256 - off] : 0;
        __syncthreads();
        scn[t] += a; scn[t + 256] += c;
        __syncthreads();
    }
    const int nodebase = b << 9;
    const int base = bstart[b];
    int e0 = scn[t] - hist[t];                 // exclusive within bucket
    int e1 = scn[t + 256] - hist[t + 256];
    sexc[b * 512 + t]       = e0;              // handoff to placeB
    sexc[b * 512 + t + 256] = e1;
    int node = nodebase + t;
    if (node < n) { rowptr[node] = base + e0; dinv[node] = rsqrtf((float)(hist[t] + 1)); }
    node = nodebase + 256 + t;
    if (node < n) { rowptr[node] = base + e1; dinv[node] = rsqrtf((float)(hist[t + 256] + 1)); }
}

// ---------------- pass 2b: LDS reorder -> coalesced final epack (scan reused from placeA) ----------------
__global__ __launch_bounds__(256) void k_placeB(const unsigned* __restrict__ ebuck,
                                                const int* __restrict__ astart,
                                                const int* __restrict__ gtail,
                                                const int* __restrict__ bstart,
                                                const int* __restrict__ sexc,
                                                const float* __restrict__ dinv,
                                                unsigned* epack, int n) {
    __shared__ int hist[512];
    __shared__ int scn[512];
    __shared__ float dloc[512];
    __shared__ unsigned outb[OUT_CAP];       // 40 KB
    const int b = blockIdx.x, t = threadIdx.x;
    const int nodebase = b << 9;
    hist[t] = 0; hist[t + 256] = 0;
    scn[t]       = sexc[b * 512 + t];
    scn[t + 256] = sexc[b * 512 + t + 256];
    dloc[t]       = (nodebase + t       < n) ? dinv[nodebase + t]       : 0.f;
    dloc[t + 256] = (nodebase + 256 + t < n) ? dinv[nodebase + 256 + t] : 0.f;
    __syncthreads();
    const int s0 = astart[b], s1 = gtail[b];
    const int base = bstart[b];
    for (int i = s0 + t; i < s1; i += 256) {
        unsigned en = ebuck[i];
        int dlow = en >> 16;
        int s = en & 0xffffu;
        int pos = scn[dlow] + atomicAdd(&hist[dlow], 1);
        unsigned word = pack_sw(s, dinv[s] * dloc[dlow]);
        if (pos < OUT_CAP) outb[pos] = word;
        else __builtin_nontemporal_store(word, &epack[base + pos]);   // overflow fallback
    }
    __syncthreads();
    int total = s1 - s0; if (total > OUT_CAP) total = OUT_CAP;
    for (int j = t; j < total; j += 256) epack[base + j] = outb[j];
}

// derive BN scale/shift from sums into LDS
__device__ inline void bn_to_lds(const float* __restrict__ sums, const float* __restrict__ g,
                                 const float* __restrict__ be, float* sc_s, float* sh_s,
                                 float inv_n, int tid) {
    if (tid < 128) {
        float m  = sums[tid] * inv_n;
        float v  = sums[128 + tid] * inv_n - m * m;
        float rs = rsqrtf(v + BN_EPS);
        float s  = g[tid] * rs;
        sc_s[tid] = s;
        sh_s[tid] = be[tid] - m * s;
    }
}

// ---------------- MFMA GEMM: C[n x 128] = act(A) @ W -> packed bf16 ----------------
template<int MODE>
__global__ __launch_bounds__(256) void k_mm_mfma(const void* __restrict__ Aptr,
                                                 const unsigned* __restrict__ wfrag,
                                                 const float* __restrict__ sums,
                                                 const float* __restrict__ g,
                                                 const float* __restrict__ be, float inv_n,
                                                 unsigned* __restrict__ outb, int n) {
    __shared__ float sc_s[128], sh_s[128];
    __shared__ float dtile[4][16][130];
    const int tid = threadIdx.x;
    if (MODE == 1) {
        bn_to_lds(sums, g, be, sc_s, sh_s, inv_n, tid);
        __syncthreads();
    }
    const int wave = tid >> 6, lane = tid & 63;
    const int r0 = blockIdx.x * 64 + wave * 16;
    const int arow = r0 + (lane & 15);
    const int koff = (lane >> 4) * 8;

    FragU afr[4];
    if (MODE == 0) {
        const float* A = (const float*)Aptr;
#pragma unroll
        for (int ks = 0; ks < 4; ks++) {
            float4 v0 = make_float4(0.f, 0.f, 0.f, 0.f), v1 = v0;
            if (arow < n) {
                v0 = *(const float4*)&A[(size_t)arow * 128 + ks * 32 + koff];
                v1 = *(const float4*)&A[(size_t)arow * 128 + ks * 32 + koff + 4];
            }
            afr[ks].u[0] = pack_bf(v0.x, v0.y);
            afr[ks].u[1] = pack_bf(v0.z, v0.w);
            afr[ks].u[2] = pack_bf(v1.x, v1.y);
            afr[ks].u[3] = pack_bf(v1.z, v1.w);
        }
    } else {
        const unsigned* Ab = (const unsigned*)Aptr;
#pragma unroll
        for (int ks = 0; ks < 4; ks++) {
            uint4 v = make_uint4(0u, 0u, 0u, 0u);
            if (arow < n) v = *(const uint4*)&Ab[(size_t)arow * 64 + ks * 16 + (lane >> 4) * 4];
            unsigned vv[4] = {v.x, v.y, v.z, v.w};
            const int kk = ks * 32 + koff;
#pragma unroll
            for (int q = 0; q < 4; q++) {
                int k0 = kk + 2 * q;
                float lo = fmaxf(fmaf(bflo(vv[q]), sc_s[k0],     sh_s[k0]),     0.f);
                float hi = fmaxf(fmaf(bfhi(vv[q]), sc_s[k0 + 1], sh_s[k0 + 1]), 0.f);
                afr[ks].u[q] = pack_bf(lo, hi);
            }
        }
    }

    const uint4* wf4 = (const uint4*)wfrag;
    const int drow = (lane >> 4) * 4;
#pragma unroll
    for (int ct = 0; ct < 8; ct++) {
        f32x4 acc = {0.f, 0.f, 0.f, 0.f};
#pragma unroll
        for (int ks = 0; ks < 4; ks++) {
            FragU b;
            *(uint4*)b.u = wf4[(ks * 8 + ct) * 64 + lane];
            acc = __builtin_amdgcn_mfma_f32_16x16x32_bf16(afr[ks].f, b.f, acc, 0, 0, 0);
        }
        const int dcol = ct * 16 + (lane & 15);
#pragma unroll
        for (int r = 0; r < 4; r++) dtile[wave][drow + r][dcol] = acc[r];
    }
    // wave-private transpose readback
    const int lr = lane >> 2;
    const int uc = (lane & 3) * 16;
    if (r0 + lr < n) {
#pragma unroll
        for (int q2 = 0; q2 < 4; q2++) {
            const float* s = &dtile[wave][lr][2 * uc + 8 * q2];
            uint4 pk;
            pk.x = pack_bf(s[0], s[1]);
            pk.y = pack_bf(s[2], s[3]);
            pk.z = pack_bf(s[4], s[5]);
            pk.w = pack_bf(s[6], s[7]);
            *(uint4*)&outb[(size_t)(r0 + lr) * 64 + uc + 4 * q2] = pk;
        }
    }
}

// ---------------- JK max (BN'd, 3-way) + MFMA projection -> fp32 out ----------------
__global__ __launch_bounds__(256) void k_jk_mfma(const unsigned* __restrict__ Bb,
                                                 const unsigned* __restrict__ Cb,
                                                 const unsigned* __restrict__ Db,
                                                 const unsigned* __restrict__ wpf,
                                                 const float* __restrict__ sumsL1,
                                                 const float* __restrict__ g1, const float* __restrict__ be1,
                                                 const float* __restrict__ sumsL2,
                                                 const float* __restrict__ g2, const float* __restrict__ be2,
                                                 float inv_n,
                                                 const float* __restrict__ b3,
                                                 const float* __restrict__ bp,
                                                 float* __restrict__ out, int n) {
    __shared__ float sc1[128], sh1[128], sc2[128], sh2[128];
    __shared__ float dtile[4][16][68];
    const int tid = threadIdx.x;
    bn_to_lds(sumsL1, g1, be1, sc1, sh1, inv_n, tid);
    bn_to_lds(sumsL2, g2, be2, sc2, sh2, inv_n, tid);
    __syncthreads();
    const int wave = tid >> 6, lane = tid & 63;
    const int r0 = blockIdx.x * 64 + wave * 16;
    const int arow = r0 + (lane & 15);
    const int koff = (lane >> 4) * 8;

    FragU afr[4];
#pragma unroll
    for (int ks = 0; ks < 4; ks++) {
        uint4 vb = make_uint4(0u,0u,0u,0u), vc = vb, vd = vb;
        if (arow < n) {
            size_t gi = (size_t)arow * 64 + ks * 16 + (lane >> 4) * 4;
            vb = *(const uint4*)&Bb[gi];
            vc = *(const uint4*)&Cb[gi];
            vd = *(const uint4*)&Db[gi];
        }
        unsigned bu[4] = {vb.x, vb.y, vb.z, vb.w};
        unsigned cu[4] = {vc.x, vc.y, vc.z, vc.w};
        unsigned du[4] = {vd.x, vd.y, vd.z, vd.w};
        const int kk = ks * 32 + koff;
#pragma unroll
        for (int q = 0; q < 4; q++) {
            int k0 = kk + 2 * q;
            float h1a = fmaxf(fmaf(bflo(bu[q]), sc1[k0],     sh1[k0]),     0.f);
            float h1b = fmaxf(fmaf(bfhi(bu[q]), sc1[k0 + 1], sh1[k0 + 1]), 0.f);
            float h2a = fmaxf(fmaf(bflo(cu[q]), sc2[k0],     sh2[k0]),     0.f);
            float h2b = fmaxf(fmaf(bfhi(cu[q]), sc2[k0 + 1], sh2[k0 + 1]), 0.f);
            float h3a = bflo(du[q]) + b3[k0];
            float h3b = bfhi(du[q]) + b3[k0 + 1];
            afr[ks].u[q] = pack_bf(fmaxf(fmaxf(h1a, h2a), h3a),
                                   fmaxf(fmaxf(h1b, h2b), h3b));
        }
    }

    const uint4* wf4 = (const uint4*)wpf;
    const int drow = (lane >> 4) * 4;
#pragma unroll
    for (int ct = 0; ct < 4; ct++) {
        f32x4 acc = {0.f, 0.f, 0.f, 0.f};
#pragma unroll
        for (int ks = 0; ks < 4; ks++) {
            FragU b;
            *(uint4*)b.u = wf4[(ks * 4 + ct) * 64 + lane];
            acc = __builtin_amdgcn_mfma_f32_16x16x32_bf16(afr[ks].f, b.f, acc, 0, 0, 0);
        }
        const int dcol = ct * 16 + (lane & 15);
        const float bb = bp[dcol];
#pragma unroll
        for (int r = 0; r < 4; r++) dtile[wave][drow + r][dcol] = acc[r] + bb;
    }
    // wave-private transpose readback -> fp32 out
    const int lr = lane >> 2;
    const int uc = (lane & 3) * 16;
    if (r0 + lr < n) {
#pragma unroll
        for (int q2 = 0; q2 < 4; q2++) {
            *(float4*)&out[(size_t)(r0 + lr) * 64 + uc + 4 * q2] =
                *(const float4*)&dtile[wave][lr][uc + 4 * q2];
        }
    }
}

// ---------------- pull aggregation: 64 lanes/node, 16-deep then 8-deep unroll ----------------
__global__ __launch_bounds__(256) void k_gather_bf(const unsigned int* __restrict__ linb,
                                                   const float* __restrict__ dinv,
                                                   const int* __restrict__ rowptr,
                                                   const unsigned* __restrict__ epack,
                                                   unsigned int* __restrict__ outb, int n) {
    const int t = threadIdx.x & 63;                          // feats 2t, 2t+1
    int node = blockIdx.x * 4 + (threadIdx.x >> 6);
    if (node >= n) return;
    node = __builtin_amdgcn_readfirstlane(node);
    const float dd = dinv[node];
    int p0 = rowptr[node];
    int p1 = rowptr[node + 1];
    p0 = __builtin_amdgcn_readfirstlane(p0);
    p1 = __builtin_amdgcn_readfirstlane(p1);

    float a0 = 0.f, a1 = 0.f, b0 = 0.f, b1 = 0.f;
    float c0 = 0.f, c1 = 0.f, d0 = 0.f, d1 = 0.f;
    int p = p0;
    for (; p + 16 <= p1; p += 16) {
        unsigned ee[16];
#pragma unroll
        for (int j = 0; j < 16; j++) ee[j] = epack[p + j];
        unsigned vv[16];
#pragma unroll
        for (int j = 0; j < 16; j++) vv[j] = linb[(size_t)(ee[j] & 0xffffu) * 64 + t];
#pragma unroll
        for (int j = 0; j < 16; j += 4) {
            float w0 = unpack_w(ee[j]), w1 = unpack_w(ee[j+1]);
            float w2 = unpack_w(ee[j+2]), w3 = unpack_w(ee[j+3]);
            a0 += bflo(vv[j])   * w0; a1 += bfhi(vv[j])   * w0;
            b0 += bflo(vv[j+1]) * w1; b1 += bfhi(vv[j+1]) * w1;
            c0 += bflo(vv[j+2]) * w2; c1 += bfhi(vv[j+2]) * w2;
            d0 += bflo(vv[j+3]) * w3; d1 += bfhi(vv[j+3]) * w3;
        }
    }
    for (; p + 8 <= p1; p += 8) {
        unsigned e0 = epack[p+0], e1 = epack[p+1], e2 = epack[p+2], e3 = epack[p+3];
        unsigned e4 = epack[p+4], e5 = epack[p+5], e6 = epack[p+6], e7 = epack[p+7];
        unsigned v0 = linb[(size_t)(e0 & 0xffffu) * 64 + t];
        unsigned v1 = linb[(size_t)(e1 & 0xffffu) * 64 + t];
        unsigned v2 = linb[(size_t)(e2 & 0xffffu) * 64 + t];
        unsigned v3 = linb[(size_t)(e3 & 0xffffu) * 64 + t];
        unsigned v4 = linb[(size_t)(e4 & 0xffffu) * 64 + t];
        unsigned v5 = linb[(size_t)(e5 & 0xffffu) * 64 + t];
        unsigned v6 = linb[(size_t)(e6 & 0xffffu) * 64 + t];
        unsigned v7 = linb[(size_t)(e7 & 0xffffu) * 64 + t];
        float w0 = unpack_w(e0), w1 = unpack_w(e1), w2 = unpack_w(e2), w3 = unpack_w(e3);
        float w4 = unpack_w(e4), w5 = unpack_w(e5), w6 = unpack_w(e6), w7 = unpack_w(e7);
        a0 += bflo(v0) * w0; a1 += bfhi(v0) * w0;
        b0 += bflo(v1) * w1; b1 += bfhi(v1) * w1;
        c0 += bflo(v2) * w2; c1 += bfhi(v2) * w2;
        d0 += bflo(v3) * w3; d1 += bfhi(v3) * w3;
        a0 += bflo(v4) * w4; a1 += bfhi(v4) * w4;
        b0 += bflo(v5) * w5; b1 += bfhi(v5) * w5;
        c0 += bflo(v6) * w6; c1 += bfhi(v6) * w6;
        d0 += bflo(v7) * w7; d1 += bfhi(v7) * w7;
    }
    for (; p < p1; p++) {
        unsigned ep = epack[p];
        unsigned v = linb[(size_t)(ep & 0xffffu) * 64 + t];
        float w = unpack_w(ep);
        a0 += bflo(v) * w; a1 += bfhi(v) * w;
    }
    {   // self-loop
        unsigned vs = linb[(size_t)node * 64 + t];
        float wsl = dd * dd;
        a0 += bflo(vs) * wsl; a1 += bfhi(vs) * wsl;
    }
    float F0 = (a0 + b0) + (c0 + d0);
    float F1 = (a1 + b1) + (c1 + d1);
    outb[(size_t)node * 64 + t] = pack_bf(F0, F1);
}

// ---------------- column stats from bf16 rows ----------------
__global__ __launch_bounds__(256) void k_colstats_bf(const unsigned int* __restrict__ hb,
                                                     float* sums, int n) {
    __shared__ float red[4][4][64];          // {slo,shi,qlo,qhi}[sub][t]
    int t = threadIdx.x & 63, sub = threadIdx.x >> 6;
    int r1 = min(blockIdx.x * 256 + 256, n);
    float s0 = 0.f, s1 = 0.f, q0 = 0.f, q1 = 0.f;
    for (int r = blockIdx.x * 256 + sub; r < r1; r += 4) {
        unsigned int v = hb[(size_t)r * 64 + t];
        float a = bflo(v), b = bfhi(v);
        s0 += a; q0 += a * a;
        s1 += b; q1 += b * b;
    }
    red[0][sub][t] = s0; red[1][sub][t] = s1;
    red[2][sub][t] = q0; red[3][sub][t] = q1;
    __syncthreads();
    if (sub == 0) {
        float ts0 = red[0][0][t] + red[0][1][t] + red[0][2][t] + red[0][3][t];
        float ts1 = red[1][0][t] + red[1][1][t] + red[1][2][t] + red[1][3][t];
        float tq0 = red[2][0][t] + red[2][1][t] + red[2][2][t] + red[2][3][t];
        float tq1 = red[3][0][t] + red[3][1][t] + red[3][2][t] + red[3][3][t];
        atomicAdd(&sums[2 * t],           ts0);
        atomicAdd(&sums[2 * t + 1],       ts1);
        atomicAdd(&sums[128 + 2 * t],     tq0);
        atomicAdd(&sums[128 + 2 * t + 1], tq1);
    }
}

extern "C" void kernel_launch(void* const* d_in, const int* in_sizes, int n_in,
                              void* d_out, int out_size, void* d_ws, size_t ws_size,
                              hipStream_t stream) {
    const float* x   = (const float*)d_in[0];
    const int*   ei  = (const int*)d_in[1];
    const float* W1  = (const float*)d_in[2];
    // b1 (d_in[3]) cancels inside BatchNorm — skipped
    const float* g1  = (const float*)d_in[4];
    const float* be1 = (const float*)d_in[5];
    const float* W2  = (const float*)d_in[6];
    // b2 (d_in[7]) cancels — skipped
    const float* g2  = (const float*)d_in[8];
    const float* be2 = (const float*)d_in[9];
    const float* W3  = (const float*)d_in[10];
    const float* b3  = (const float*)d_in[11];
    const float* Wp  = (const float*)d_in[12];
    const float* bp  = (const float*)d_in[13];
    float* out = (float*)d_out;

    const int n = in_sizes[0] / F_IN;        // 50000 (< 65536: u16 src packing valid)
    const int e = in_sizes[1] / 2;           // 800000
    const int* src = ei;
    const int* dst = ei + e;
    const int nb = (n + 511) >> 9;           // 98 buckets of 512 nodes (nb <= 128)

    float* ws = (float*)d_ws;
    float*        dinv   = ws;                               // n
    unsigned int* Ab     = (unsigned int*)(ws + n);          // n*64  lin bf16
    unsigned int* Bb     = Ab + (size_t)n * 64;              // n*64  conv1 raw bf16
    unsigned int* Cb     = Bb + (size_t)n * 64;              // n*64  conv2 raw bf16
    unsigned int* Db     = Cb + (size_t)n * 64;              // n*64  conv3 raw bf16
    int*          rowptr = (int*)(Db + (size_t)n * 64);      // n+2
    int*          bstart = rowptr + n + 2;                   // nb+1
    int*          astart = bstart + nb + 1;                  // nb+1
    int*          gtail  = astart + nb + 1;                  // nb
    unsigned*     epack  = (unsigned*)(gtail + nb);          // e
    unsigned*     ebuck  = epack + e;                        // e + 16*(nb+1) staging
    int*          bhs    = (int*)(ebuck + e + 16 * (nb + 1)); // HIST_BLOCKS*128 slices
    int*          sexc   = bhs + HIST_BLOCKS * 128;          // nb*512 scan handoff
    float*        sumsL1 = (float*)(sexc + nb * 512);        // 256 (zeroed in k_histw)
    float*        sumsL2 = sumsL1 + 256;                     // 256 (zeroed in k_histw)
    unsigned*     wfr    = (unsigned*)(sumsL2 + 256);        // 3*8192 + 4096 bf16 W fragments

    const int BT = 256;
    const int gN  = (n + BT - 1) / BT;                       // 196
    const int gMM = (n + 63) / 64;                           // 782
    const int gG  = (n + 3) / 4;                             // 4 nodes (waves) / block
    const float inv_n = 1.0f / (float)n;

    // ----- merged: bucket hist (also zeroes sums) || W-fragment conversion -----
    k_histw<<<HIST_BLOCKS + WCONV_BLOCKS, 256, 0, stream>>>(dst, bhs, sumsL1, e,
                                                            W1, W2, W3, Wp, wfr);
    k_prep<<<1, 256, 0, stream>>>(bhs, bstart, astart, gtail, rowptr, nb, n, e);
    k_bin<<<BIN_BLOCKS, 256, 0, stream>>>(src, dst, gtail, ebuck, e, nb);
    k_placeA<<<nb, 256, 0, stream>>>(ebuck, astart, gtail, bstart, rowptr, dinv, sexc, n);
    k_placeB<<<nb, 256, 0, stream>>>(ebuck, astart, gtail, bstart, sexc, dinv, epack, n);

    // ----- layer 1: lin1 = x@W1 (MFMA) ; aggregate ; stats -----
    k_mm_mfma<0><<<gMM, 256, 0, stream>>>(x, wfr, nullptr, nullptr, nullptr, 0.f, Ab, n);
    k_gather_bf<<<gG, 256, 0, stream>>>(Ab, dinv, rowptr, epack, Bb, n);
    k_colstats_bf<<<gN, 256, 0, stream>>>(Bb, sumsL1, n);

    // ----- layer 2: lin2 = relu(bn1(Bb))@W2 (MFMA) ; aggregate ; stats -----
    k_mm_mfma<1><<<gMM, 256, 0, stream>>>(Bb, wfr + 8192, sumsL1, g1, be1, inv_n, Ab, n);
    k_gather_bf<<<gG, 256, 0, stream>>>(Ab, dinv, rowptr, epack, Cb, n);
    k_colstats_bf<<<gN, 256, 0, stream>>>(Cb, sumsL2, n);

    // ----- layer 3: lin3 = relu(bn2(Cb))@W3 (MFMA) ; aggregate -----
    k_mm_mfma<1><<<gMM, 256, 0, stream>>>(Cb, wfr + 16384, sumsL2, g2, be2, inv_n, Ab, n);
    k_gather_bf<<<gG, 256, 0, stream>>>(Ab, dinv, rowptr, epack, Db, n);

    // ----- JK max + MFMA projection -----
    k_jk_mfma<<<gMM, 256, 0, stream>>>(Bb, Cb, Db, wfr + 24576,
                                       sumsL1, g1, be1, sumsL2, g2, be2,
                                       inv_n, b3, bp, out, n);
}

// Round 19
// 296.953 us; speedup vs baseline: 1.3454x; 1.0612x over previous
//
#include <hip/hip_runtime.h>

#define F_IN 128
#define H    128
#define OUT  64
#define BN_EPS 1e-5f
#define BIN_BLOCKS 160
#define HIST_BLOCKS 256
#define WCONV_BLOCKS 28
#define NSHADOW 32        // BN stat shadow copies (each 256 floats)
#define BUF_CAP 64        // per-bucket LDS staging entries in k_bin
#define OUT_CAP 10240     // per-bucket LDS reorder buffer in k_placeB (40KB)

typedef __attribute__((ext_vector_type(8))) short bf16x8;
typedef __attribute__((ext_vector_type(4))) float f32x4;
typedef __attribute__((ext_vector_type(4))) unsigned uint32x4;   // native vec for NT stores
union FragU { unsigned u[4]; bf16x8 f; };

// ---------------- bf16 / fp16 helpers ----------------
__device__ inline float bflo(unsigned int v) { return __uint_as_float(v << 16); }
__device__ inline float bfhi(unsigned int v) { return __uint_as_float(v & 0xffff0000u); }
__device__ inline unsigned int pack_bf(float a, float b) {
    unsigned int ua = __float_as_uint(a), ub = __float_as_uint(b);
    ua = (ua + 0x7fffu + ((ua >> 16) & 1u)) >> 16;          // RNE
    ub = (ub + 0x7fffu + ((ub >> 16) & 1u)) >> 16;
    return ua | (ub << 16);
}
union f16u { unsigned short u; _Float16 f; };
__device__ inline unsigned pack_sw(int s, float w) {        // src:u16 | fp16 w:u16
    f16u c; c.f = (_Float16)w;
    return (unsigned)s | ((unsigned)c.u << 16);
}
__device__ inline float unpack_w(unsigned p) {
    f16u c; c.u = (unsigned short)(p >> 16);
    return (float)c.f;
}

// ---------------- merged: bucket histogram (blocks < HIST_BLOCKS) || W-fragment conv ----------------
// Blocks 0..(2*NSHADOW*2/..): zero the shadow BN sums (2 layers x NSHADOW x 256 floats).
__global__ __launch_bounds__(256) void k_histw(const int* __restrict__ dst, int* bhs,
                                               float* sums_all, int e,
                                               const float* __restrict__ W1,
                                               const float* __restrict__ W2,
                                               const float* __restrict__ W3,
                                               const float* __restrict__ Wp,
                                               unsigned* __restrict__ wf) {
    __shared__ int h[128];
    const int t = threadIdx.x;
    if (blockIdx.x < HIST_BLOCKS) {
        if (t < 128) h[t] = 0;
        if (blockIdx.x < 2 * NSHADOW)                      // 64 blocks x 256 = 16384 floats
            sums_all[blockIdx.x * 256 + t] = 0.f;
        __syncthreads();
        for (int i = blockIdx.x * 256 + t; i < e; i += HIST_BLOCKS * 256)
            atomicAdd(&h[dst[i] >> 9], 1);
        __syncthreads();
        if (t < 128) bhs[blockIdx.x * 128 + t] = h[t];
        return;
    }
    // ---- W fragment conversion ----
    int g = (blockIdx.x - HIST_BLOCKS) * 256 + t;            // 0..7167
    if (g < 6144) {
        int w = g >> 11;
        int rem = g & 2047;
        int ks = rem >> 9;
        int ct = (rem >> 6) & 7;
        int lane = rem & 63;
        const float* W = (w == 0) ? W1 : (w == 1) ? W2 : W3;
        int col = ct * 16 + (lane & 15);
        int kb = ks * 32 + (lane >> 4) * 8;
        uint4 pk;
        pk.x = pack_bf(W[(kb + 0) * 128 + col], W[(kb + 1) * 128 + col]);
        pk.y = pack_bf(W[(kb + 2) * 128 + col], W[(kb + 3) * 128 + col]);
        pk.z = pack_bf(W[(kb + 4) * 128 + col], W[(kb + 5) * 128 + col]);
        pk.w = pack_bf(W[(kb + 6) * 128 + col], W[(kb + 7) * 128 + col]);
        ((uint4*)(wf + (size_t)w * 8192))[(ks * 8 + ct) * 64 + lane] = pk;
    } else if (g < 7168) {
        int rem = g - 6144;                      // Wp: 128x64
        int ks = rem >> 8;
        int ct = (rem >> 6) & 3;
        int lane = rem & 63;
        int col = ct * 16 + (lane & 15);
        int kb = ks * 32 + (lane >> 4) * 8;
        uint4 pk;
        pk.x = pack_bf(Wp[(kb + 0) * 64 + col], Wp[(kb + 1) * 64 + col]);
        pk.y = pack_bf(Wp[(kb + 2) * 64 + col], Wp[(kb + 3) * 64 + col]);
        pk.z = pack_bf(Wp[(kb + 4) * 64 + col], Wp[(kb + 5) * 64 + col]);
        pk.w = pack_bf(Wp[(kb + 6) * 64 + col], Wp[(kb + 7) * 64 + col]);
        ((uint4*)(wf + 24576))[(ks * 4 + ct) * 64 + lane] = pk;
    }
}

// ---------------- prep: reduce slices -> bucket sizes -> bstart + staging starts ----------------
__global__ __launch_bounds__(256) void k_prep(const int* __restrict__ bhs,
                                              int* bstart, int* astart, int* gtail,
                                              int* rowptr, int nb, int n, int e) {
    __shared__ int part[256];
    __shared__ int bs[128];
    const int t = threadIdx.x;
    const int b = t & 127, half = t >> 7;
    int v = 0;
    for (int s = half * (HIST_BLOCKS / 2); s < (half + 1) * (HIST_BLOCKS / 2); s++)
        v += bhs[s * 128 + b];
    part[t] = v;
    __syncthreads();
    int tot = (t < 128) ? (part[t] + part[t + 128]) : 0;
    if (t < 128) bs[t] = tot;
    __syncthreads();
    for (int off = 1; off < 128; off <<= 1) {
        int x = (t < 128 && t >= off) ? bs[t - off] : 0;
        __syncthreads();
        if (t < 128) bs[t] += x;
        __syncthreads();
    }
    if (t < nb) {
        int excl = bs[t] - tot;                 // exclusive scan
        bstart[t] = excl;
        int a = ((excl + 15) & ~15) + 16 * t;   // 64B-aligned staging start, disjoint
        astart[t] = a;
        gtail[t] = a;
    }
    if (t == 0) { bstart[nb] = e; rowptr[n] = e; }
}

// ---------------- pass 1: LDS-binned scatter to staging (uint32x4 NT flushes) ----------------
__global__ __launch_bounds__(256) void k_bin(const int* __restrict__ src, const int* __restrict__ dst,
                                             int* gtail, unsigned* ebuck, int e, int nb) {
    __shared__ unsigned buf[128 * BUF_CAP];  // 32 KB
    __shared__ int cnt[128];
    const int t = threadIdx.x;
    if (t < 128) cnt[t] = 0;
    __syncthreads();
    const int per = (e + gridDim.x - 1) / gridDim.x;
    const int lo = blockIdx.x * per;
    const int hi = min(e, lo + per);
    for (int base = lo; base < hi; base += 1024) {
#pragma unroll
        for (int k = 0; k < 4; k++) {
            int i = base + k * 256 + t;
            if (i < hi) {
                int d = dst[i];
                int b = d >> 9;
                unsigned entry = (unsigned)src[i] | ((unsigned)(d & 511) << 16);
                int slot = atomicAdd(&cnt[b], 1);
                if (slot < BUF_CAP) buf[b * BUF_CAP + slot] = entry;
                else {                               // overflow fallback (never for random input)
                    int pos = atomicAdd(&gtail[b], 1);
                    __builtin_nontemporal_store(entry, &ebuck[pos]);
                }
            }
        }
        __syncthreads();
        if (t < nb) {                                // flush full 16-entry chunks as uint32x4
            int c = cnt[t]; if (c > BUF_CAP) c = BUF_CAP;
            int full = c & ~15;
            if (full > 0) {
                int bp = atomicAdd(&gtail[t], full);
                uint32x4* dst4 = (uint32x4*)&ebuck[bp];
                const uint32x4* src4 = (const uint32x4*)&buf[t * BUF_CAP];
                for (int j4 = 0; j4 < (full >> 2); j4++)
                    __builtin_nontemporal_store(src4[j4], &dst4[j4]);
                int rem = c - full;
                for (int j = 0; j < rem; j++) buf[t * BUF_CAP + j] = buf[t * BUF_CAP + full + j];
                cnt[t] = rem;
            }
        }
        __syncthreads();
    }
    if (t < nb) {                                    // final drain (vec quads + word tail)
        int c = cnt[t]; if (c > BUF_CAP) c = BUF_CAP;
        if (c > 0) {
            int bp = atomicAdd(&gtail[t], c);        // bp 16-aligned here (all prior bumps x16)
            int q = c >> 2;
            uint32x4* dst4 = (uint32x4*)&ebuck[bp];
            const uint32x4* src4 = (const uint32x4*)&buf[t * BUF_CAP];
            for (int j4 = 0; j4 < q; j4++)
                __builtin_nontemporal_store(src4[j4], &dst4[j4]);
            for (int j = q << 2; j < c; j++)
                __builtin_nontemporal_store(buf[t * BUF_CAP + j], &ebuck[bp + j]);
        }
    }
}

// ---------------- pass 2a: per-bucket hist -> rowptr + dinv + exported exclusive scan ----------------
__global__ __launch_bounds__(256) void k_placeA(const unsigned* __restrict__ ebuck,
                                                const int* __restrict__ astart,
                                                const int* __restrict__ gtail,
                                                const int* __restrict__ bstart,
                                                int* rowptr, float* dinv, int* sexc, int n) {
    __shared__ int hist[512];
    __shared__ int scn[512];
    const int b = blockIdx.x, t = threadIdx.x;
    hist[t] = 0; hist[t + 256] = 0;
    __syncthreads();
    const int s0 = astart[b], s1 = gtail[b];
    for (int i = s0 + t; i < s1; i += 256) atomicAdd(&hist[ebuck[i] >> 16], 1);
    __syncthreads();
    scn[t] = hist[t]; scn[t + 256] = hist[t + 256];
    __syncthreads();
    for (int off = 1; off < 512; off <<= 1) {
        int a = (t >= off) ? scn[t - off] : 0;
        int c = (t + 256 >= off) ? scn[t + 256 - off] : 0;
        __syncthreads();
        scn[t] += a; scn[t + 256] += c;
        __syncthreads();
    }
    const int nodebase = b << 9;
    const int base = bstart[b];
    int e0 = scn[t] - hist[t];                 // exclusive within bucket
    int e1 = scn[t + 256] - hist[t + 256];
    sexc[b * 512 + t]       = e0;              // handoff to placeB
    sexc[b * 512 + t + 256] = e1;
    int node = nodebase + t;
    if (node < n) { rowptr[node] = base + e0; dinv[node] = rsqrtf((float)(hist[t] + 1)); }
    node = nodebase + 256 + t;
    if (node < n) { rowptr[node] = base + e1; dinv[node] = rsqrtf((float)(hist[t + 256] + 1)); }
}

// ---------------- pass 2b: LDS reorder -> coalesced final epack (scan reused from placeA) ----------------
__global__ __launch_bounds__(256) void k_placeB(const unsigned* __restrict__ ebuck,
                                                const int* __restrict__ astart,
                                                const int* __restrict__ gtail,
                                                const int* __restrict__ bstart,
                                                const int* __restrict__ sexc,
                                                const float* __restrict__ dinv,
                                                unsigned* epack, int n) {
    __shared__ int hist[512];
    __shared__ int scn[512];
    __shared__ float dloc[512];
    __shared__ unsigned outb[OUT_CAP];       // 40 KB
    const int b = blockIdx.x, t = threadIdx.x;
    const int nodebase = b << 9;
    hist[t] = 0; hist[t + 256] = 0;
    scn[t]       = sexc[b * 512 + t];
    scn[t + 256] = sexc[b * 512 + t + 256];
    dloc[t]       = (nodebase + t       < n) ? dinv[nodebase + t]       : 0.f;
    dloc[t + 256] = (nodebase + 256 + t < n) ? dinv[nodebase + 256 + t] : 0.f;
    __syncthreads();
    const int s0 = astart[b], s1 = gtail[b];
    const int base = bstart[b];
    for (int i = s0 + t; i < s1; i += 256) {
        unsigned en = ebuck[i];
        int dlow = en >> 16;
        int s = en & 0xffffu;
        int pos = scn[dlow] + atomicAdd(&hist[dlow], 1);
        unsigned word = pack_sw(s, dinv[s] * dloc[dlow]);
        if (pos < OUT_CAP) outb[pos] = word;
        else __builtin_nontemporal_store(word, &epack[base + pos]);   // overflow fallback
    }
    __syncthreads();
    int total = s1 - s0; if (total > OUT_CAP) total = OUT_CAP;
    for (int j = t; j < total; j += 256) epack[base + j] = outb[j];
}

// derive BN scale/shift from NSHADOW shadow sums into LDS
__device__ inline void bn_to_lds(const float* __restrict__ sums, const float* __restrict__ g,
                                 const float* __restrict__ be, float* sc_s, float* sh_s,
                                 float inv_n, int tid) {
    if (tid < 128) {
        float s = 0.f, q = 0.f;
#pragma unroll
        for (int c = 0; c < NSHADOW; c++) {
            s += sums[c * 256 + tid];
            q += sums[c * 256 + 128 + tid];
        }
        float m  = s * inv_n;
        float v  = q * inv_n - m * m;
        float rs = rsqrtf(v + BN_EPS);
        float sf = g[tid] * rs;
        sc_s[tid] = sf;
        sh_s[tid] = be[tid] - m * sf;
    }
}

// ---------------- MFMA GEMM: C[n x 128] = act(A) @ W -> packed bf16 ----------------
template<int MODE>
__global__ __launch_bounds__(256) void k_mm_mfma(const void* __restrict__ Aptr,
                                                 const unsigned* __restrict__ wfrag,
                                                 const float* __restrict__ sums,
                                                 const float* __restrict__ g,
                                                 const float* __restrict__ be, float inv_n,
                                                 unsigned* __restrict__ outb, int n) {
    __shared__ float sc_s[128], sh_s[128];
    __shared__ float dtile[4][16][130];
    const int tid = threadIdx.x;
    if (MODE == 1) {
        bn_to_lds(sums, g, be, sc_s, sh_s, inv_n, tid);
        __syncthreads();
    }
    const int wave = tid >> 6, lane = tid & 63;
    const int r0 = blockIdx.x * 64 + wave * 16;
    const int arow = r0 + (lane & 15);
    const int koff = (lane >> 4) * 8;

    FragU afr[4];
    if (MODE == 0) {
        const float* A = (const float*)Aptr;
#pragma unroll
        for (int ks = 0; ks < 4; ks++) {
            float4 v0 = make_float4(0.f, 0.f, 0.f, 0.f), v1 = v0;
            if (arow < n) {
                v0 = *(const float4*)&A[(size_t)arow * 128 + ks * 32 + koff];
                v1 = *(const float4*)&A[(size_t)arow * 128 + ks * 32 + koff + 4];
            }
            afr[ks].u[0] = pack_bf(v0.x, v0.y);
            afr[ks].u[1] = pack_bf(v0.z, v0.w);
            afr[ks].u[2] = pack_bf(v1.x, v1.y);
            afr[ks].u[3] = pack_bf(v1.z, v1.w);
        }
    } else {
        const unsigned* Ab = (const unsigned*)Aptr;
#pragma unroll
        for (int ks = 0; ks < 4; ks++) {
            uint4 v = make_uint4(0u, 0u, 0u, 0u);
            if (arow < n) v = *(const uint4*)&Ab[(size_t)arow * 64 + ks * 16 + (lane >> 4) * 4];
            unsigned vv[4] = {v.x, v.y, v.z, v.w};
            const int kk = ks * 32 + koff;
#pragma unroll
            for (int q = 0; q < 4; q++) {
                int k0 = kk + 2 * q;
                float lo = fmaxf(fmaf(bflo(vv[q]), sc_s[k0],     sh_s[k0]),     0.f);
                float hi = fmaxf(fmaf(bfhi(vv[q]), sc_s[k0 + 1], sh_s[k0 + 1]), 0.f);
                afr[ks].u[q] = pack_bf(lo, hi);
            }
        }
    }

    const uint4* wf4 = (const uint4*)wfrag;
    const int drow = (lane >> 4) * 4;
#pragma unroll
    for (int ct = 0; ct < 8; ct++) {
        f32x4 acc = {0.f, 0.f, 0.f, 0.f};
#pragma unroll
        for (int ks = 0; ks < 4; ks++) {
            FragU b;
            *(uint4*)b.u = wf4[(ks * 8 + ct) * 64 + lane];
            acc = __builtin_amdgcn_mfma_f32_16x16x32_bf16(afr[ks].f, b.f, acc, 0, 0, 0);
        }
        const int dcol = ct * 16 + (lane & 15);
#pragma unroll
        for (int r = 0; r < 4; r++) dtile[wave][drow + r][dcol] = acc[r];
    }
    // wave-private transpose readback
    const int lr = lane >> 2;
    const int uc = (lane & 3) * 16;
    if (r0 + lr < n) {
#pragma unroll
        for (int q2 = 0; q2 < 4; q2++) {
            const float* s = &dtile[wave][lr][2 * uc + 8 * q2];
            uint4 pk;
            pk.x = pack_bf(s[0], s[1]);
            pk.y = pack_bf(s[2], s[3]);
            pk.z = pack_bf(s[4], s[5]);
            pk.w = pack_bf(s[6], s[7]);
            *(uint4*)&outb[(size_t)(r0 + lr) * 64 + uc + 4 * q2] = pk;
        }
    }
}

// ---------------- JK max (BN'd, 3-way) + MFMA projection -> fp32 out ----------------
__global__ __launch_bounds__(256) void k_jk_mfma(const unsigned* __restrict__ Bb,
                                                 const unsigned* __restrict__ Cb,
                                                 const unsigned* __restrict__ Db,
                                                 const unsigned* __restrict__ wpf,
                                                 const float* __restrict__ sumsL1,
                                                 const float* __restrict__ g1, const float* __restrict__ be1,
                                                 const float* __restrict__ sumsL2,
                                                 const float* __restrict__ g2, const float* __restrict__ be2,
                                                 float inv_n,
                                                 const float* __restrict__ b3,
                                                 const float* __restrict__ bp,
                                                 float* __restrict__ out, int n) {
    __shared__ float sc1[128], sh1[128], sc2[128], sh2[128];
    __shared__ float dtile[4][16][68];
    const int tid = threadIdx.x;
    bn_to_lds(sumsL1, g1, be1, sc1, sh1, inv_n, tid);
    bn_to_lds(sumsL2, g2, be2, sc2, sh2, inv_n, tid);
    __syncthreads();
    const int wave = tid >> 6, lane = tid & 63;
    const int r0 = blockIdx.x * 64 + wave * 16;
    const int arow = r0 + (lane & 15);
    const int koff = (lane >> 4) * 8;

    FragU afr[4];
#pragma unroll
    for (int ks = 0; ks < 4; ks++) {
        uint4 vb = make_uint4(0u,0u,0u,0u), vc = vb, vd = vb;
        if (arow < n) {
            size_t gi = (size_t)arow * 64 + ks * 16 + (lane >> 4) * 4;
            vb = *(const uint4*)&Bb[gi];
            vc = *(const uint4*)&Cb[gi];
            vd = *(const uint4*)&Db[gi];
        }
        unsigned bu[4] = {vb.x, vb.y, vb.z, vb.w};
        unsigned cu[4] = {vc.x, vc.y, vc.z, vc.w};
        unsigned du[4] = {vd.x, vd.y, vd.z, vd.w};
        const int kk = ks * 32 + koff;
#pragma unroll
        for (int q = 0; q < 4; q++) {
            int k0 = kk + 2 * q;
            float h1a = fmaxf(fmaf(bflo(bu[q]), sc1[k0],     sh1[k0]),     0.f);
            float h1b = fmaxf(fmaf(bfhi(bu[q]), sc1[k0 + 1], sh1[k0 + 1]), 0.f);
            float h2a = fmaxf(fmaf(bflo(cu[q]), sc2[k0],     sh2[k0]),     0.f);
            float h2b = fmaxf(fmaf(bfhi(cu[q]), sc2[k0 + 1], sh2[k0 + 1]), 0.f);
            float h3a = bflo(du[q]) + b3[k0];
            float h3b = bfhi(du[q]) + b3[k0 + 1];
            afr[ks].u[q] = pack_bf(fmaxf(fmaxf(h1a, h2a), h3a),
                                   fmaxf(fmaxf(h1b, h2b), h3b));
        }
    }

    const uint4* wf4 = (const uint4*)wpf;
    const int drow = (lane >> 4) * 4;
#pragma unroll
    for (int ct = 0; ct < 4; ct++) {
        f32x4 acc = {0.f, 0.f, 0.f, 0.f};
#pragma unroll
        for (int ks = 0; ks < 4; ks++) {
            FragU b;
            *(uint4*)b.u = wf4[(ks * 4 + ct) * 64 + lane];
            acc = __builtin_amdgcn_mfma_f32_16x16x32_bf16(afr[ks].f, b.f, acc, 0, 0, 0);
        }
        const int dcol = ct * 16 + (lane & 15);
        const float bb = bp[dcol];
#pragma unroll
        for (int r = 0; r < 4; r++) dtile[wave][drow + r][dcol] = acc[r] + bb;
    }
    // wave-private transpose readback -> fp32 out
    const int lr = lane >> 2;
    const int uc = (lane & 3) * 16;
    if (r0 + lr < n) {
#pragma unroll
        for (int q2 = 0; q2 < 4; q2++) {
            *(float4*)&out[(size_t)(r0 + lr) * 64 + uc + 4 * q2] =
                *(const float4*)&dtile[wave][lr][uc + 4 * q2];
        }
    }
}

// ---------------- pull aggregation (+ optional fused BN column stats) ----------------
template<int STATS>
__global__ __launch_bounds__(256) void k_gather_bf(const unsigned int* __restrict__ linb,
                                                   const float* __restrict__ dinv,
                                                   const int* __restrict__ rowptr,
                                                   const unsigned* __restrict__ epack,
                                                   unsigned int* __restrict__ outb,
                                                   float* __restrict__ sums, int n) {
    __shared__ float red[4][4][64];
    const int t = threadIdx.x & 63;                          // feats 2t, 2t+1
    const int wave = threadIdx.x >> 6;
    int node = blockIdx.x * 4 + wave;
    float F0 = 0.f, F1 = 0.f;
    if (node < n) {
        node = __builtin_amdgcn_readfirstlane(node);
        const float dd = dinv[node];
        int p0 = __builtin_amdgcn_readfirstlane(rowptr[node]);
        int p1 = __builtin_amdgcn_readfirstlane(rowptr[node + 1]);

        float a0 = 0.f, a1 = 0.f, b0 = 0.f, b1 = 0.f;
        float c0 = 0.f, c1 = 0.f, d0 = 0.f, d1 = 0.f;
        int p = p0;
        for (; p + 16 <= p1; p += 16) {
            unsigned ee[16];
#pragma unroll
            for (int j = 0; j < 16; j++) ee[j] = epack[p + j];
            unsigned vv[16];
#pragma unroll
            for (int j = 0; j < 16; j++) vv[j] = linb[(size_t)(ee[j] & 0xffffu) * 64 + t];
#pragma unroll
            for (int j = 0; j < 16; j += 4) {
                float w0 = unpack_w(ee[j]), w1 = unpack_w(ee[j+1]);
                float w2 = unpack_w(ee[j+2]), w3 = unpack_w(ee[j+3]);
                a0 += bflo(vv[j])   * w0; a1 += bfhi(vv[j])   * w0;
                b0 += bflo(vv[j+1]) * w1; b1 += bfhi(vv[j+1]) * w1;
                c0 += bflo(vv[j+2]) * w2; c1 += bfhi(vv[j+2]) * w2;
                d0 += bflo(vv[j+3]) * w3; d1 += bfhi(vv[j+3]) * w3;
            }
        }
        for (; p + 8 <= p1; p += 8) {
            unsigned e0 = epack[p+0], e1 = epack[p+1], e2 = epack[p+2], e3 = epack[p+3];
            unsigned e4 = epack[p+4], e5 = epack[p+5], e6 = epack[p+6], e7 = epack[p+7];
            unsigned v0 = linb[(size_t)(e0 & 0xffffu) * 64 + t];
            unsigned v1 = linb[(size_t)(e1 & 0xffffu) * 64 + t];
            unsigned v2 = linb[(size_t)(e2 & 0xffffu) * 64 + t];
            unsigned v3 = linb[(size_t)(e3 & 0xffffu) * 64 + t];
            unsigned v4 = linb[(size_t)(e4 & 0xffffu) * 64 + t];
            unsigned v5 = linb[(size_t)(e5 & 0xffffu) * 64 + t];
            unsigned v6 = linb[(size_t)(e6 & 0xffffu) * 64 + t];
            unsigned v7 = linb[(size_t)(e7 & 0xffffu) * 64 + t];
            float w0 = unpack_w(e0), w1 = unpack_w(e1), w2 = unpack_w(e2), w3 = unpack_w(e3);
            float w4 = unpack_w(e4), w5 = unpack_w(e5), w6 = unpack_w(e6), w7 = unpack_w(e7);
            a0 += bflo(v0) * w0; a1 += bfhi(v0) * w0;
            b0 += bflo(v1) * w1; b1 += bfhi(v1) * w1;
            c0 += bflo(v2) * w2; c1 += bfhi(v2) * w2;
            d0 += bflo(v3) * w3; d1 += bfhi(v3) * w3;
            a0 += bflo(v4) * w4; a1 += bfhi(v4) * w4;
            b0 += bflo(v5) * w5; b1 += bfhi(v5) * w5;
            c0 += bflo(v6) * w6; c1 += bfhi(v6) * w6;
            d0 += bflo(v7) * w7; d1 += bfhi(v7) * w7;
        }
        for (; p < p1; p++) {
            unsigned ep = epack[p];
            unsigned v = linb[(size_t)(ep & 0xffffu) * 64 + t];
            float w = unpack_w(ep);
            a0 += bflo(v) * w; a1 += bfhi(v) * w;
        }
        {   // self-loop
            unsigned vs = linb[(size_t)node * 64 + t];
            float wsl = dd * dd;
            a0 += bflo(vs) * wsl; a1 += bfhi(vs) * wsl;
        }
        float rx = (a0 + b0) + (c0 + d0);
        float ry = (a1 + b1) + (c1 + d1);
        unsigned pk = pack_bf(rx, ry);
        outb[(size_t)node * 64 + t] = pk;
        if (STATS) { F0 = bflo(pk); F1 = bfhi(pk); }   // stats of rounded values
    }
    if (STATS) {
        red[0][wave][t] = F0;       red[1][wave][t] = F1;
        red[2][wave][t] = F0 * F0;  red[3][wave][t] = F1 * F1;
        __syncthreads();
        if (threadIdx.x < 64) {
            float ts0 = red[0][0][t] + red[0][1][t] + red[0][2][t] + red[0][3][t];
            float ts1 = red[1][0][t] + red[1][1][t] + red[1][2][t] + red[1][3][t];
            float tq0 = red[2][0][t] + red[2][1][t] + red[2][2][t] + red[2][3][t];
            float tq1 = red[3][0][t] + red[3][1][t] + red[3][2][t] + red[3][3][t];
            float* base = sums + (blockIdx.x & (NSHADOW - 1)) * 256;
            atomicAdd(&base[2 * t],           ts0);
            atomicAdd(&base[2 * t + 1],       ts1);
            atomicAdd(&base[128 + 2 * t],     tq0);
            atomicAdd(&base[128 + 2 * t + 1], tq1);
        }
    }
}

extern "C" void kernel_launch(void* const* d_in, const int* in_sizes, int n_in,
                              void* d_out, int out_size, void* d_ws, size_t ws_size,
                              hipStream_t stream) {
    const float* x   = (const float*)d_in[0];
    const int*   ei  = (const int*)d_in[1];
    const float* W1  = (const float*)d_in[2];
    // b1 (d_in[3]) cancels inside BatchNorm — skipped
    const float* g1  = (const float*)d_in[4];
    const float* be1 = (const float*)d_in[5];
    const float* W2  = (const float*)d_in[6];
    // b2 (d_in[7]) cancels — skipped
    const float* g2  = (const float*)d_in[8];
    const float* be2 = (const float*)d_in[9];
    const float* W3  = (const float*)d_in[10];
    const float* b3  = (const float*)d_in[11];
    const float* Wp  = (const float*)d_in[12];
    const float* bp  = (const float*)d_in[13];
    float* out = (float*)d_out;

    const int n = in_sizes[0] / F_IN;        // 50000 (< 65536: u16 src packing valid)
    const int e = in_sizes[1] / 2;           // 800000
    const int* src = ei;
    const int* dst = ei + e;
    const int nb = (n + 511) >> 9;           // 98 buckets of 512 nodes (nb <= 128)

    float* ws = (float*)d_ws;
    float*        dinv   = ws;                               // n
    unsigned int* Ab     = (unsigned int*)(ws + n);          // n*64  lin bf16
    unsigned int* Bb     = Ab + (size_t)n * 64;              // n*64  conv1 raw bf16
    unsigned int* Cb     = Bb + (size_t)n * 64;              // n*64  conv2 raw bf16
    unsigned int* Db     = Cb + (size_t)n * 64;              // n*64  conv3 raw bf16
    int*          rowptr = (int*)(Db + (size_t)n * 64);      // n+2
    int*          bstart = rowptr + n + 2;                   // nb+1
    int*          astart = bstart + nb + 1;                  // nb+1
    int*          gtail  = astart + nb + 1;                  // nb
    unsigned*     epack  = (unsigned*)(gtail + nb);          // e
    unsigned*     ebuck  = epack + e;                        // e + 16*(nb+1) staging
    int*          bhs    = (int*)(ebuck + e + 16 * (nb + 1)); // HIST_BLOCKS*128 slices
    int*          sexc   = bhs + HIST_BLOCKS * 128;          // nb*512 scan handoff
    float*        sumsL1 = (float*)(sexc + nb * 512);        // NSHADOW*256 (zeroed in k_histw)
    float*        sumsL2 = sumsL1 + NSHADOW * 256;           // NSHADOW*256 (zeroed in k_histw)
    unsigned*     wfr    = (unsigned*)(sumsL2 + NSHADOW * 256); // 3*8192 + 4096 bf16 W fragments

    const int gMM = (n + 63) / 64;                           // 782
    const int gG  = (n + 3) / 4;                             // 4 nodes (waves) / block
    const float inv_n = 1.0f / (float)n;

    // ----- merged: bucket hist (also zeroes shadow sums) || W-fragment conversion -----
    k_histw<<<HIST_BLOCKS + WCONV_BLOCKS, 256, 0, stream>>>(dst, bhs, sumsL1, e,
                                                            W1, W2, W3, Wp, wfr);
    k_prep<<<1, 256, 0, stream>>>(bhs, bstart, astart, gtail, rowptr, nb, n, e);
    k_bin<<<BIN_BLOCKS, 256, 0, stream>>>(src, dst, gtail, ebuck, e, nb);
    k_placeA<<<nb, 256, 0, stream>>>(ebuck, astart, gtail, bstart, rowptr, dinv, sexc, n);
    k_placeB<<<nb, 256, 0, stream>>>(ebuck, astart, gtail, bstart, sexc, dinv, epack, n);

    // ----- layer 1: lin1 = x@W1 (MFMA) ; aggregate + fused stats -----
    k_mm_mfma<0><<<gMM, 256, 0, stream>>>(x, wfr, nullptr, nullptr, nullptr, 0.f, Ab, n);
    k_gather_bf<1><<<gG, 256, 0, stream>>>(Ab, dinv, rowptr, epack, Bb, sumsL1, n);

    // ----- layer 2: lin2 = relu(bn1(Bb))@W2 (MFMA) ; aggregate + fused stats -----
    k_mm_mfma<1><<<gMM, 256, 0, stream>>>(Bb, wfr + 8192, sumsL1, g1, be1, inv_n, Ab, n);
    k_gather_bf<1><<<gG, 256, 0, stream>>>(Ab, dinv, rowptr, epack, Cb, sumsL2, n);

    // ----- layer 3: lin3 = relu(bn2(Cb))@W3 (MFMA) ; aggregate -----
    k_mm_mfma<1><<<gMM, 256, 0, stream>>>(Cb, wfr + 16384, sumsL2, g2, be2, inv_n, Ab, n);
    k_gather_bf<0><<<gG, 256, 0, stream>>>(Ab, dinv, rowptr, epack, Db, nullptr, n);

    // ----- JK max + MFMA projection -----
    k_jk_mfma<<<gMM, 256, 0, stream>>>(Bb, Cb, Db, wfr + 24576,
                                       sumsL1, g1, be1, sumsL2, g2, be2,
                                       inv_n, b3, bp, out, n);
}